// Round 5
// baseline (1602.999 us; speedup 1.0000x reference)
//
#include <hip/hip_runtime.h>
#include <cmath>

typedef unsigned short u16;
typedef unsigned int   u32;
typedef short s16x8 __attribute__((ext_vector_type(8)));
typedef float f32x4 __attribute__((ext_vector_type(4)));

#define D_  1024
#define H_  16
#define NL_ 6
#define B_  16
#define L_  64
#define T_  192
#define NB_ 100
#define DF_ 4096
#define BT_ (B_*T_)   /* 3072 rows in stream */
#define BL_ (B_*L_)   /* 1024 rows per modality */

__device__ __forceinline__ float b2f(u16 u){ u32 x = ((u32)u)<<16; return __uint_as_float(x); }
__device__ __forceinline__ u16 f2b(float f){ u32 x = __float_as_uint(f); x += 0x7fffu + ((x>>16)&1u); return (u16)(x>>16); }
__device__ __forceinline__ float gelu_f(float v){ return 0.5f*v*(1.0f+erff(v*0.70710678118f)); }

// async global->LDS, 16B per lane. LDS dest is wave-uniform base + lane*16.
typedef const unsigned int __attribute__((address_space(1)))* as1_u32p;
typedef unsigned int __attribute__((address_space(3)))* as3_u32p;
__device__ __forceinline__ void gload16(const void* g, void* l)
{
    __builtin_amdgcn_global_load_lds((as1_u32p)g, (as3_u32p)l, 16, 0, 0);
}

// ---------------------------------------------------------------------------
// Transpose + f32->bf16 convert core: W[K][N] f32 -> Wt[N][K] bf16, 64x64 tile
// ---------------------------------------------------------------------------
__device__ __forceinline__ void tconv_tile(const float* __restrict__ W,
                                           u16* __restrict__ Wt,
                                           int K, int N, int nb, int kb, int tid)
{
    __shared__ float tile[64][65];
    int tr = tid >> 4, tc = tid & 15;
#pragma unroll
    for (int rr = 0; rr < 4; ++rr) {
        int k = tr + rr*16;
        float4 v = *(const float4*)(W + (size_t)(kb + k)*N + nb + tc*4);
        tile[k][tc*4+0] = v.x; tile[k][tc*4+1] = v.y;
        tile[k][tc*4+2] = v.z; tile[k][tc*4+3] = v.w;
    }
    __syncthreads();
#pragma unroll
    for (int rr = 0; rr < 4; ++rr) {
        int n = tr + rr*16;
        ushort4 o;
        o.x = f2b(tile[tc*4+0][n]);
        o.y = f2b(tile[tc*4+1][n]);
        o.z = f2b(tile[tc*4+2][n]);
        o.w = f2b(tile[tc*4+3][n]);
        *(ushort4*)(Wt + (size_t)(nb + n)*K + kb + tc*4) = o;
    }
}

// generic single-matrix version (embed w2 weights)
__global__ __launch_bounds__(256) void tconv_kernel(const float* __restrict__ W,
                                                    u16* __restrict__ Wt,
                                                    int K, int N)
{
    tconv_tile(W, Wt, K, N, blockIdx.x*64, blockIdx.y*64, threadIdx.x);
}

// per-layer FUSED conversion of all weights (QKV, P, Wm1, Wm2): grid 3072 flat
__global__ __launch_bounds__(256) void tconvL_kernel(const float* __restrict__ Wq,
                                                     const float* __restrict__ Wk,
                                                     const float* __restrict__ Wv,
                                                     const float* __restrict__ Wp,
                                                     const float* __restrict__ Wm1,
                                                     const float* __restrict__ Wm2,
                                                     u16* __restrict__ Wqkvt,
                                                     u16* __restrict__ Wpt,
                                                     u16* __restrict__ Wm1t,
                                                     u16* __restrict__ Wm2t,
                                                     int layer)
{
    size_t DD = (size_t)D_*D_, DDF = (size_t)D_*DF_;
    int t = blockIdx.x;
    if (t < 1024) {
        int sel = t >> 8, tt = t & 255;
        const float* Wz = ((sel == 0) ? Wq : (sel == 1) ? Wk : (sel == 2) ? Wv : Wp) + layer*DD;
        u16* Wtz = (sel == 3) ? (Wpt + layer*DD) : (Wqkvt + layer*3*DD + sel*DD);
        tconv_tile(Wz, Wtz, D_, D_, (tt & 15)*64, (tt >> 4)*64, threadIdx.x);
    } else if (t < 2048) {
        int t2 = t - 1024;     // Wm1: K=D_, N=DF_; 64 n-tiles x 16 k-tiles
        tconv_tile(Wm1 + layer*DDF, Wm1t + layer*DDF, D_, DF_, (t2 & 63)*64, (t2 >> 6)*64, threadIdx.x);
    } else {
        int t2 = t - 2048;     // Wm2: K=DF_, N=D_; 16 n-tiles x 64 k-tiles
        tconv_tile(Wm2 + layer*DDF, Wm2t + layer*DDF, DF_, D_, (t2 & 15)*64, (t2 >> 4)*64, threadIdx.x);
    }
}

// bqkv[layer][3*1024] = concat(bq[layer], bk[layer], bv[layer])
__global__ __launch_bounds__(256) void pack_qkv_bias_kernel(const float* __restrict__ bq,
                                                            const float* __restrict__ bk,
                                                            const float* __restrict__ bv,
                                                            float* __restrict__ out)
{
    int i = blockIdx.x*256 + threadIdx.x;      // NL_*3072 = 18432 exactly
    int layer = i / 3072;
    int r = i - layer*3072;
    int c = r >> 10, d = r & 1023;
    const float* src = (c == 0) ? bq : (c == 1) ? bk : bv;
    out[i] = src[layer*1024 + d];
}

// lin_w (1024x27) -> lin_wT (27x1024) f32
__global__ __launch_bounds__(256) void tlin_kernel(const float* __restrict__ w,
                                                   float* __restrict__ wt)
{
    int k = blockIdx.x*256 + threadIdx.x;      // 1024
#pragma unroll 1
    for (int c = 0; c < 27; ++c)
        wt[c*1024 + k] = w[k*27 + c];
}

// ---------------------------------------------------------------------------
// Small VALU GEMM for the K=91 / K=27 embedding first layers (trivial FLOPs).
// ---------------------------------------------------------------------------
__global__ __launch_bounds__(256) void embed1_kernel(const float* __restrict__ A,
                                                     const float* __restrict__ W,
                                                     const float* __restrict__ bias,
                                                     u16* __restrict__ out, int K)
{
    int idx = blockIdx.x*256 + threadIdx.x;     // 1024*1024 outputs
    int m = idx >> 10, n = idx & 1023;
    float acc = bias[n];
    for (int k = 0; k < K; ++k)
        acc += A[m*K + k] * W[k*1024 + n];
    out[idx] = f2b(gelu_f(acc));
}

// ---------------------------------------------------------------------------
// rtg embedding
// ---------------------------------------------------------------------------
__global__ __launch_bounds__(128) void rtg_kernel(const float* __restrict__ rtgs,
                                                  const float* __restrict__ ret_w,
                                                  const float* __restrict__ res_w,
                                                  const float* __restrict__ bucket_w,
                                                  const float* __restrict__ bucket_b,
                                                  float* __restrict__ eR)
{
    int r = blockIdx.x, tid = threadIdx.x;
    __shared__ float sarr[NB_];
    __shared__ float red[128];
    float rtg = rtgs[r];
    float s = 0.f;
    if (tid < NB_) {
        float v = rtg * ret_w[tid];
        s = (v > 0.f) ? v : 0.01f*v;
        sarr[tid] = s;
    }
    __syncthreads();
    float s2 = -1e30f;
    if (tid < NB_) {
        float acc = s;
        for (int m = 0; m < NB_; ++m) acc += sarr[m] * res_w[m*NB_ + tid];
        s2 = acc;
    }
    red[tid] = s2; __syncthreads();
    for (int off = 64; off > 0; off >>= 1) { if (tid < off) red[tid] = fmaxf(red[tid], red[tid+off]); __syncthreads(); }
    float mx = red[0]; __syncthreads();
    float e = (tid < NB_) ? expf(s2 - mx) : 0.f;
    red[tid] = e; __syncthreads();
    for (int off = 64; off > 0; off >>= 1) { if (tid < off) red[tid] += red[tid+off]; __syncthreads(); }
    float S = red[0]; __syncthreads();
    float bv = (100.f/99.f) * (float)tid;
    red[tid] = e * bv; __syncthreads();
    for (int off = 64; off > 0; off >>= 1) { if (tid < off) red[tid] += red[tid+off]; __syncthreads(); }
    float EB = red[0];
    float inv = 1.f/(1e-8f + S);
    float c = EB * inv, sg = S * inv;
    for (int d = tid; d < D_; d += 128)
        eR[(size_t)r*D_ + d] = c*bucket_w[d] + sg*bucket_b[d];
}

// ---------------------------------------------------------------------------
// assemble: x[b,3l+c,:] = emb_c[b,l,:] + pos[3l+c,:]   (f32 stream)
// ---------------------------------------------------------------------------
__global__ __launch_bounds__(256) void assemble_kernel(const float* __restrict__ eR,
                                                       const float* __restrict__ eS,
                                                       const float* __restrict__ eA,
                                                       const float* __restrict__ pos,
                                                       float* __restrict__ xf)
{
    int idx = blockIdx.x*256 + threadIdx.x;       // BT_*D_
    int row = idx >> 10, d = idx & 1023;
    int b = row / T_, t = row % T_;
    int l = t / 3, c = t % 3;
    const float* src = (c == 0) ? eR : (c == 1) ? eS : eA;
    xf[idx] = src[(size_t)(b*L_ + l)*D_ + d] + pos[(size_t)t*D_ + d];
}

// ---------------------------------------------------------------------------
// LayerNorm, wave-per-row (4 rows/block, no LDS, no barriers).
// NP=4: row = x + sum of 4 split-K partial slabs; summed row written to xout.
// ---------------------------------------------------------------------------
template<int NP>
__global__ __launch_bounds__(256) void ln_kernel(const float* __restrict__ x,
                                                 const float* __restrict__ parts,
                                                 size_t pstride,
                                                 const float* __restrict__ g,
                                                 const float* __restrict__ bb,
                                                 float* __restrict__ xout,
                                                 u16* __restrict__ out)
{
    int row = blockIdx.x*4 + (threadIdx.x >> 6);
    int lane = threadIdx.x & 63;
    const float4* xr = (const float4*)(x + (size_t)row*D_);
    float4 v[4];
    float s = 0.f, q = 0.f;
#pragma unroll
    for (int i = 0; i < 4; ++i) {
        float4 a = xr[lane + i*64];
        if (NP == 4) {
#pragma unroll
            for (int z = 0; z < 4; ++z) {
                float4 p = ((const float4*)(parts + (size_t)z*pstride + (size_t)row*D_))[lane + i*64];
                a.x += p.x; a.y += p.y; a.z += p.z; a.w += p.w;
            }
        }
        v[i] = a;
        s += a.x+a.y+a.z+a.w;
        q += a.x*a.x+a.y*a.y+a.z*a.z+a.w*a.w;
    }
    if (NP == 4) {
#pragma unroll
        for (int i = 0; i < 4; ++i)
            ((float4*)(xout + (size_t)row*D_))[lane + i*64] = v[i];
    }
#pragma unroll
    for (int off = 1; off < 64; off <<= 1) {
        s += __shfl_xor(s, off, 64);
        q += __shfl_xor(q, off, 64);
    }
    float mean = s*(1.f/(float)D_);
    float var  = q*(1.f/(float)D_) - mean*mean;
    float rstd = rsqrtf(var + 1e-5f);
#pragma unroll
    for (int i = 0; i < 4; ++i) {
        int d0 = (lane + i*64)*4;
        ushort4 ov;
        ov.x = f2b((v[i].x-mean)*rstd*g[d0+0] + bb[d0+0]);
        ov.y = f2b((v[i].y-mean)*rstd*g[d0+1] + bb[d0+1]);
        ov.z = f2b((v[i].z-mean)*rstd*g[d0+2] + bb[d0+2]);
        ov.w = f2b((v[i].w-mean)*rstd*g[d0+3] + bb[d0+3]);
        ((ushort4*)(out + (size_t)row*D_))[lane + i*64] = ov;
    }
}

// ---------------------------------------------------------------------------
// MFMA bf16 GEMM: C(MxN) = act(A(MxK) @ Wt(NxK)^T + bias) [+res].
// 128x128 tile / 4 waves / BK=32 / 16x16x32 MFMA. 3-slab counted-vmcnt pipe.
// SPLITK>1: blockIdx.z owns K-chunk kc; ATOMIC ? atomicAdd into outF
// : plain store to outF + z*partStride (reduced later in fused LN).
// RES (SPLITK==1 only): v += res[off] after activation (fused residual).
// ---------------------------------------------------------------------------
template<int GELU_ACT, int SPLITK, int ATOMIC, int RES>
__global__ __launch_bounds__(256) void gemm_bt(const u16* __restrict__ A,
                                               const u16* __restrict__ Bt,
                                               const float* __restrict__ bias,
                                               const float* __restrict__ res,
                                               float* __restrict__ outF,
                                               u16* __restrict__ outB,
                                               int M, int N, int K, int kc,
                                               size_t partStride)
{
    __shared__ __align__(16) u16 As[3*128*32];
    __shared__ __align__(16) u16 Bs[3*128*32];
    int tid = threadIdx.x;

    int gx = gridDim.x;
    int nwg = gx * gridDim.y;
    int id = blockIdx.y * gx + blockIdx.x;
    int q8 = nwg >> 3;                         // nwg % 8 == 0 for all launches
    int nid = (id & 7) * q8 + (id >> 3);       // contiguous tile range per XCD
    int n0 = (nid % gx) * 128;
    int m0 = (nid / gx) * 128;

    int wave = tid >> 6, lane = tid & 63;
    int wm = (wave >> 1) * 64, wn = (wave & 1) * 64;
    int lr = lane & 15, lq = lane >> 4;
    int slotRd = (lq ^ ((lr >> 1) & 3)) * 8;   // swizzled k-slot (u16 units)

    int srow = tid >> 2;                       // staging row 0..63 (+64)
    int sslot = (tid & 3) ^ ((srow >> 1) & 3); // swizzled source col-block

    int k0 = (SPLITK > 1) ? blockIdx.z * kc : 0;
    int nIt = ((SPLITK > 1) ? kc : K) >> 5;

    const u16* ap0 = A  + (size_t)(m0 + srow) * K + k0 + sslot * 8;
    const u16* ap1 = ap0 + (size_t)64 * K;
    const u16* bp0 = Bt + (size_t)(n0 + srow) * K + k0 + sslot * 8;
    const u16* bp1 = bp0 + (size_t)64 * K;

    // slab base pointers (rotate each iteration; reads from sA0, stage into sA2)
    u16 *sA0 = As, *sA1 = As + 4096, *sA2 = As + 8192;
    u16 *sB0 = Bs, *sB1 = Bs + 4096, *sB2 = Bs + 8192;
    int woff = wave * 512;

    f32x4 acc[4][4];
#pragma unroll
    for (int i = 0; i < 4; ++i)
#pragma unroll
        for (int j = 0; j < 4; ++j) acc[i][j] = (f32x4){0.f,0.f,0.f,0.f};

    // prologue: stage tiles 0 and 1 (order matters for vmcnt counting)
    gload16(ap0, sA0 + woff); gload16(ap1, sA0 + 2048 + woff);
    gload16(bp0, sB0 + woff); gload16(bp1, sB0 + 2048 + woff);
    ap0 += 32; ap1 += 32; bp0 += 32; bp1 += 32;
    gload16(ap0, sA1 + woff); gload16(ap1, sA1 + 2048 + woff);
    gload16(bp0, sB1 + woff); gload16(bp1, sB1 + 2048 + woff);
    ap0 += 32; ap1 += 32; bp0 += 32; bp1 += 32;

    for (int it = 0; it < nIt; ++it) {
        if (it + 1 < nIt) asm volatile("s_waitcnt vmcnt(4)" ::: "memory");
        else              asm volatile("s_waitcnt vmcnt(0)" ::: "memory");
        asm volatile("s_barrier" ::: "memory");
        if (it + 2 < nIt) {                    // stage tile t+2 into slab2
            gload16(ap0, sA2 + woff); gload16(ap1, sA2 + 2048 + woff);
            gload16(bp0, sB2 + woff); gload16(bp1, sB2 + 2048 + woff);
            ap0 += 32; ap1 += 32; bp0 += 32; bp1 += 32;
        }
        s16x8 af[4], bf[4];
#pragma unroll
        for (int i = 0; i < 4; ++i)
            af[i] = *(const s16x8*)(sA0 + (wm + i*16 + lr)*32 + slotRd);
#pragma unroll
        for (int j = 0; j < 4; ++j)
            bf[j] = *(const s16x8*)(sB0 + (wn + j*16 + lr)*32 + slotRd);
#pragma unroll
        for (int i = 0; i < 4; ++i)
#pragma unroll
            for (int j = 0; j < 4; ++j)
                acc[i][j] = __builtin_amdgcn_mfma_f32_16x16x32_bf16(af[i], bf[j], acc[i][j], 0, 0, 0);
        // rotate slabs: t+1 becomes current, freed slab becomes stage target
        u16* t0 = sA0; sA0 = sA1; sA1 = sA2; sA2 = t0;
        u16* t1 = sB0; sB0 = sB1; sB1 = sB2; sB2 = t1;
    }

    float* outZ = (SPLITK > 1 && !ATOMIC) ? outF + (size_t)blockIdx.z * partStride : outF;
#pragma unroll
    for (int i = 0; i < 4; ++i) {
        int mbase = m0 + wm + i*16 + lq*4;
#pragma unroll
        for (int j = 0; j < 4; ++j) {
            int n = n0 + wn + j*16 + lr;
            float bvl = (SPLITK > 1) ? ((blockIdx.z == 0) ? bias[n] : 0.f) : bias[n];
#pragma unroll
            for (int r = 0; r < 4; ++r) {
                int m = mbase + r;
                float v = acc[i][j][r] + bvl;
                size_t off = (size_t)m*N + n;
                if (SPLITK > 1) {
                    if (ATOMIC) atomicAdd(outF + off, v);
                    else        outZ[off] = v;
                } else {
                    if (GELU_ACT) v = gelu_f(v);
                    if (RES)      v += res[off];
                    if (outF) outF[off] = v;
                    if (outB) outB[off] = f2b(v);
                }
            }
        }
    }
}

// ---------------------------------------------------------------------------
// MFMA flash-style attention. Grid (B*H, 3): blockIdx.y = causal chunk c;
// block handles q-tiles c*4+w (one per wave). K is NOT staged (L2-hot after
// the QKV GEMM) -- B-fragments read straight from global. Only V (transposed,
// needed for PV fragment layout) + per-wave P chunks live in LDS: 31 KB ->
// ~5 blocks/CU. Single barrier, placed AFTER QK^T/softmax so V-staging
// latency hides under compute.
// ---------------------------------------------------------------------------
__global__ __launch_bounds__(256) void attn_mfma_kernel(const u16* __restrict__ qkv,
                                                        u16* __restrict__ yb)
{
    __shared__ __align__(16) u16 Vt[64*200];
    __shared__ __align__(16) u16 Pch[4][16*40];

    int tid = threadIdx.x;
    int b = blockIdx.x >> 4, h = blockIdx.x & 15;
    int c = blockIdx.y;
    int nrows = (c + 1) * 64;
    int bT = b * T_;
    int colBase = h * 64;
    int w = tid >> 6, lane = tid & 63;
    int lr = lane & 15, lq = lane >> 4;
    const int S3 = 3 * D_;

    // stage V (transposed), rows [0, nrows)
    for (int it = 0; it < (nrows >> 5); ++it) {
        int cc = it*256 + tid;
        int row = cc >> 3, ch = cc & 7;
        union { int4 v; u16 s[8]; } rv;
        rv.v = *(const int4*)(qkv + (size_t)(bT+row)*S3 + 2*D_ + colBase + ch*8);
#pragma unroll
        for (int i2 = 0; i2 < 8; ++i2)
            Vt[(ch*8 + i2)*200 + row] = rv.s[i2];
    }

    u16* Ch = Pch[w];
    int qt = c*4 + w;                 // this wave's q-tile (0..11)
    int tqb = qt * 16;

    // Q A-fragments (global, L2-hot)
    const u16* qrow = qkv + (size_t)(bT + tqb + lr)*S3 + colBase + lq*8;
    s16x8 af0 = *(const s16x8*)(qrow);
    s16x8 af1 = *(const s16x8*)(qrow + 32);

    // S = Q K^T  (K B-fragments from global/L2; C layout: row=lq*4+r, col=lr)
    f32x4 sacc[12];
#pragma unroll
    for (int jt = 0; jt < 12; ++jt) {
        if (jt <= qt) {
            const u16* kr = qkv + (size_t)(bT + jt*16 + lr)*S3 + D_ + colBase + lq*8;
            s16x8 bk0 = *(const s16x8*)(kr);
            s16x8 bk1 = *(const s16x8*)(kr + 32);
            f32x4 a = (f32x4){0.f,0.f,0.f,0.f};
            a = __builtin_amdgcn_mfma_f32_16x16x32_bf16(af0, bk0, a, 0, 0, 0);
            a = __builtin_amdgcn_mfma_f32_16x16x32_bf16(af1, bk1, a, 0, 0, 0);
            sacc[jt] = a;
        }
    }

    // mask + row max
    float mrow[4] = {-1e30f,-1e30f,-1e30f,-1e30f};
#pragma unroll
    for (int jt = 0; jt < 12; ++jt) if (jt <= qt) {
#pragma unroll
        for (int r = 0; r < 4; ++r) {
            bool valid = (jt < qt) || (lr <= lq*4 + r);
            float s = valid ? sacc[jt][r]*0.125f : -1e30f;
            sacc[jt][r] = s;
            mrow[r] = fmaxf(mrow[r], s);
        }
    }
#pragma unroll
    for (int r = 0; r < 4; ++r) {
#pragma unroll
        for (int off = 1; off < 16; off <<= 1)
            mrow[r] = fmaxf(mrow[r], __shfl_xor(mrow[r], off, 64));
    }

    // exp + row sum (e kept in sacc registers)
    float lrow[4] = {0.f,0.f,0.f,0.f};
#pragma unroll
    for (int jt = 0; jt < 12; ++jt) if (jt <= qt) {
#pragma unroll
        for (int r = 0; r < 4; ++r) {
            float e = __expf(sacc[jt][r] - mrow[r]);
            sacc[jt][r] = e;
            lrow[r] += e;
        }
    }
#pragma unroll
    for (int r = 0; r < 4; ++r) {
#pragma unroll
        for (int off = 1; off < 16; off <<= 1)
            lrow[r] += __shfl_xor(lrow[r], off, 64);
        lrow[r] = 1.f / lrow[r];
    }

    __syncthreads();                  // V staged (hidden under QK^T+softmax)

    // PV: per 32-key chunk, write P chunk (C->A layout via LDS), mfma
    int nkt = (qt + 2) >> 1;
    f32x4 oacc[4];
#pragma unroll
    for (int nt = 0; nt < 4; ++nt) oacc[nt] = (f32x4){0.f,0.f,0.f,0.f};

#pragma unroll
    for (int kt = 0; kt < 6; ++kt) if (kt < nkt) {
        int jt0 = 2*kt, jt1 = 2*kt + 1;
#pragma unroll
        for (int r = 0; r < 4; ++r) {
            u16 e0 = f2b(sacc[jt0][r]);
            u16 e1 = (jt1 <= qt) ? f2b(sacc[jt1][r]) : (u16)0;
            Ch[(lq*4 + r)*40 + lr]      = e0;
            Ch[(lq*4 + r)*40 + 16 + lr] = e1;
        }
        s16x8 ap = *(const s16x8*)(Ch + lr*40 + lq*8);
#pragma unroll
        for (int nt = 0; nt < 4; ++nt) {
            s16x8 bv = *(const s16x8*)(Vt + (nt*16 + lr)*200 + kt*32 + lq*8);
            oacc[nt] = __builtin_amdgcn_mfma_f32_16x16x32_bf16(ap, bv, oacc[nt], 0, 0, 0);
        }
    }

    // store O (C layout), normalized by 1/l
#pragma unroll
    for (int nt = 0; nt < 4; ++nt)
#pragma unroll
        for (int r = 0; r < 4; ++r)
            yb[(size_t)(bT + tqb + lq*4 + r)*D_ + colBase + nt*16 + lr] =
                f2b(oacc[nt][r] * lrow[r]);
}

// ---------------------------------------------------------------------------
// Final linear: out(BT x 27) = (xf [+4 partials]) @ lin_wT^T + lin_b.
// One wave per row; shuffle reduce per output column.
// ---------------------------------------------------------------------------
template<int NP>
__global__ __launch_bounds__(256) void final_kernel(const float* __restrict__ xf,
                                                    const float* __restrict__ parts,
                                                    size_t pstride,
                                                    const float* __restrict__ lin_wT,
                                                    const float* __restrict__ lin_b,
                                                    float* __restrict__ out)
{
    int row = blockIdx.x*4 + (threadIdx.x >> 6);
    int lane = threadIdx.x & 63;
    const float4* xr = (const float4*)(xf + (size_t)row*D_);
    float4 x[4];
#pragma unroll
    for (int i = 0; i < 4; ++i) {
        float4 v = xr[lane + i*64];
        if (NP == 4) {
#pragma unroll
            for (int z = 0; z < 4; ++z) {
                float4 p = ((const float4*)(parts + (size_t)z*pstride + (size_t)row*D_))[lane + i*64];
                v.x += p.x; v.y += p.y; v.z += p.z; v.w += p.w;
            }
        }
        x[i] = v;
    }
#pragma unroll 1
    for (int c = 0; c < 27; ++c) {
        const float4* wr = (const float4*)(lin_wT + (size_t)c*D_);
        float a = 0.f;
#pragma unroll
        for (int i = 0; i < 4; ++i) {
            float4 wv = wr[lane + i*64];
            a += x[i].x*wv.x + x[i].y*wv.y + x[i].z*wv.z + x[i].w*wv.w;
        }
#pragma unroll
        for (int off = 1; off < 64; off <<= 1)
            a += __shfl_xor(a, off, 64);
        if (lane == 0) out[(size_t)row*27 + c] = a + lin_b[c];
    }
}

// ---------------------------------------------------------------------------
extern "C" void kernel_launch(void* const* d_in, const int* in_sizes, int n_in,
                              void* d_out, int out_size, void* d_ws, size_t ws_size,
                              hipStream_t stream)
{
    const float* states   = (const float*)d_in[0];
    const float* actions  = (const float*)d_in[1];
    const float* rtgs     = (const float*)d_in[2];
    const float* se_w1 = (const float*)d_in[5];
    const float* se_b1 = (const float*)d_in[6];
    const float* se_w2 = (const float*)d_in[7];
    const float* se_b2 = (const float*)d_in[8];
    const float* ae_w1 = (const float*)d_in[9];
    const float* ae_b1 = (const float*)d_in[10];
    const float* ae_w2 = (const float*)d_in[11];
    const float* ae_b2 = (const float*)d_in[12];
    const float* ad_bucket_w = (const float*)d_in[13];
    const float* ad_bucket_b = (const float*)d_in[14];
    const float* ad_ret_w = (const float*)d_in[15];
    const float* ad_res_w = (const float*)d_in[16];
    const float* pos_emb  = (const float*)d_in[17];
    const float* ln1_g = (const float*)d_in[18];
    const float* ln1_b = (const float*)d_in[19];
    const float* Wq = (const float*)d_in[20];
    const float* bq = (const float*)d_in[21];
    const float* Wk = (const float*)d_in[22];
    const float* bk = (const float*)d_in[23];
    const float* Wv = (const float*)d_in[24];
    const float* bv = (const float*)d_in[25];
    const float* Wp = (const float*)d_in[26];
    const float* bp = (const float*)d_in[27];
    const float* ln2_g = (const float*)d_in[28];
    const float* ln2_b = (const float*)d_in[29];
    const float* Wm1 = (const float*)d_in[30];
    const float* bm1 = (const float*)d_in[31];
    const float* Wm2 = (const float*)d_in[32];
    const float* bm2 = (const float*)d_in[33];
    const float* lin_w = (const float*)d_in[34];
    const float* lin_b = (const float*)d_in[35];

    char* w = (char*)d_ws;
    auto take = [&](size_t bytes) { char* p = w; w += (bytes + 255) & ~(size_t)255; return p; };

    float* xf   = (float*)take((size_t)BT_*D_*4);
    u16* hb     = (u16*)take((size_t)BT_*D_*2);        // ln out; also attn-y
    u16* qkvb   = (u16*)take((size_t)BT_*3*D_*2);      // fused QKV bf16
    char* scr   =        take((size_t)BT_*DF_*2);      // midb; embed scratch aliased
    u16*  midb  = (u16*)scr;
    u16*  tSb   = (u16*)scr;
    u16*  tAb   = (u16*)(scr + (size_t)BL_*D_*2);
    float* eS   = (float*)(scr + (size_t)2*BL_*D_*2);
    float* eA   = (float*)(scr + (size_t)2*BL_*D_*2 + (size_t)BL_*D_*4);
    float* eR   = (float*)(scr + (size_t)2*BL_*D_*2 + (size_t)2*BL_*D_*4);
    float* mq   = (float*)take((size_t)4*BT_*D_*4);    // MLP2 partials (4 slabs)

    // pre-transposed bf16 weights (N x K)
    u16* Wqkvt = (u16*)take((size_t)NL_*3*D_*D_*2);
    u16* Wpt   = (u16*)take((size_t)NL_*D_*D_*2);
    u16* Wm1t  = (u16*)take((size_t)NL_*D_*DF_*2);
    u16* Wm2t  = (u16*)take((size_t)NL_*DF_*D_*2);
    u16* sw2t  = (u16*)take((size_t)D_*D_*2);
    u16* aw2t  = (u16*)take((size_t)D_*D_*2);
    float* bqkv= (float*)take((size_t)NL_*3*D_*4);
    float* lwT = (float*)take((size_t)27*D_*4);

    size_t ask = (size_t)(w - (char*)d_ws);
    bool bigWS = (ws_size >= ask);   // mq slabs available?
    // (if not, MLP2 falls back to atomic split-K into xf; ln1/final use NP=0)

    const size_t PSTRIDE = (size_t)BT_*D_;
    size_t DD = (size_t)D_*D_, DDF = (size_t)D_*DF_;

    // --- small prep + layer-0 weights (JIT: layer i+1 converted during layer i) ---
    pack_qkv_bias_kernel<<<72, 256, 0, stream>>>(bq, bk, bv, bqkv);
    tlin_kernel<<<4, 256, 0, stream>>>(lin_w, lwT);
    tconv_kernel<<<dim3(16,16), 256, 0, stream>>>(se_w2, sw2t, D_, D_);
    tconv_kernel<<<dim3(16,16), 256, 0, stream>>>(ae_w2, aw2t, D_, D_);
    tconvL_kernel<<<3072, 256, 0, stream>>>(Wq, Wk, Wv, Wp, Wm1, Wm2,
                                            Wqkvt, Wpt, Wm1t, Wm2t, 0);

    // --- embeddings ---
    embed1_kernel<<<4096, 256, 0, stream>>>(states,  se_w1, se_b1, tSb, 91);
    embed1_kernel<<<4096, 256, 0, stream>>>(actions, ae_w1, ae_b1, tAb, 27);
    gemm_bt<1,1,0,0><<<dim3(8,8), 256, 0, stream>>>(tSb, sw2t, se_b2, nullptr, eS, nullptr, BL_, D_, D_, D_, 0);
    gemm_bt<0,1,0,0><<<dim3(8,8), 256, 0, stream>>>(tAb, aw2t, ae_b2, nullptr, eA, nullptr, BL_, D_, D_, D_, 0);
    rtg_kernel<<<BL_, 128, 0, stream>>>(rtgs, ad_ret_w, ad_res_w, ad_bucket_w, ad_bucket_b, eR);
    assemble_kernel<<<(BT_*D_)/256, 256, 0, stream>>>(eR, eS, eA, pos_emb, xf);

    // --- transformer layers ---
    for (int i = 0; i < NL_; ++i) {
        // ln1: layers >0 also reduce the previous MLP2 partials into xf
        if (i > 0 && bigWS)
            ln_kernel<4><<<BT_/4, 256, 0, stream>>>(xf, mq, PSTRIDE, ln1_g + i*D_, ln1_b + i*D_, xf, hb);
        else
            ln_kernel<0><<<BT_/4, 256, 0, stream>>>(xf, nullptr, 0, ln1_g + i*D_, ln1_b + i*D_, nullptr, hb);
        // fused QKV
        gemm_bt<0,1,0,0><<<dim3(24,24), 256, 0, stream>>>(hb, Wqkvt + (size_t)i*3*DD, bqkv + i*3*D_,
                                                          nullptr, nullptr, qkvb, BT_, 3*D_, D_, D_, 0);
        attn_mfma_kernel<<<dim3(B_*H_,3), 256, 0, stream>>>(qkvb, hb);   // y -> hb
        // JIT: convert next layer's weights now (L2/L3-hot when used)
        if (i + 1 < NL_)
            tconvL_kernel<<<3072, 256, 0, stream>>>(Wq, Wk, Wv, Wp, Wm1, Wm2,
                                                    Wqkvt, Wpt, Wm1t, Wm2t, i+1);
        // P projection: direct, residual fused in epilogue (xf += y @ Wp + bp)
        gemm_bt<0,1,0,1><<<dim3(8,24), 256, 0, stream>>>(hb, Wpt + (size_t)i*DD, bp + i*D_,
                                                         xf, xf, nullptr, BT_, D_, D_, D_, 0);
        // ln2 (xf already holds the updated residual stream)
        ln_kernel<0><<<BT_/4, 256, 0, stream>>>(xf, nullptr, 0, ln2_g + i*D_, ln2_b + i*D_, nullptr, hb);
        // MLP
        gemm_bt<1,1,0,0><<<dim3(32,24), 256, 0, stream>>>(hb, Wm1t + (size_t)i*DDF, bm1 + i*DF_,
                                                          nullptr, nullptr, midb, BT_, DF_, D_, D_, 0);
        if (bigWS)
            gemm_bt<0,4,0,0><<<dim3(8,24,4), 256, 0, stream>>>(midb, Wm2t + (size_t)i*DDF, bm2 + i*D_,
                                                               nullptr, mq, nullptr, BT_, D_, DF_, 1024, PSTRIDE);
        else
            gemm_bt<0,2,1,0><<<dim3(8,24,2), 256, 0, stream>>>(midb, Wm2t + (size_t)i*DDF, bm2 + i*D_,
                                                               nullptr, xf, nullptr, BT_, D_, DF_, 2048, 0);
    }

    // --- head (reduces last MLP2 partials on the fly) ---
    if (bigWS)
        final_kernel<4><<<BT_/4, 256, 0, stream>>>(xf, mq, PSTRIDE, lwT, lin_b, (float*)d_out);
    else
        final_kernel<0><<<BT_/4, 256, 0, stream>>>(xf, nullptr, 0, lwT, lin_b, (float*)d_out);
}

// Round 6
// 1557.079 us; speedup vs baseline: 1.0295x; 1.0295x over previous
//
#include <hip/hip_runtime.h>
#include <cmath>

typedef unsigned short u16;
typedef unsigned int   u32;
typedef short s16x8 __attribute__((ext_vector_type(8)));
typedef float f32x4 __attribute__((ext_vector_type(4)));

#define D_  1024
#define H_  16
#define NL_ 6
#define B_  16
#define L_  64
#define T_  192
#define NB_ 100
#define DF_ 4096
#define BT_ (B_*T_)   /* 3072 rows in stream */
#define BL_ (B_*L_)   /* 1024 rows per modality */

__device__ __forceinline__ float b2f(u16 u){ u32 x = ((u32)u)<<16; return __uint_as_float(x); }
__device__ __forceinline__ u16 f2b(float f){ u32 x = __float_as_uint(f); x += 0x7fffu + ((x>>16)&1u); return (u16)(x>>16); }
__device__ __forceinline__ float gelu_f(float v){ return 0.5f*v*(1.0f+erff(v*0.70710678118f)); }

// async global->LDS, 16B per lane. LDS dest is wave-uniform base + lane*16.
typedef const unsigned int __attribute__((address_space(1)))* as1_u32p;
typedef unsigned int __attribute__((address_space(3)))* as3_u32p;
__device__ __forceinline__ void gload16(const void* g, void* l)
{
    __builtin_amdgcn_global_load_lds((as1_u32p)g, (as3_u32p)l, 16, 0, 0);
}

// ---------------------------------------------------------------------------
// Transpose + f32->bf16 convert core: W[K][N] f32 -> Wt[N][K] bf16, 64x64 tile
// ---------------------------------------------------------------------------
__device__ __forceinline__ void tconv_tile(const float* __restrict__ W,
                                           u16* __restrict__ Wt,
                                           int K, int N, int nb, int kb, int tid)
{
    __shared__ float tile[64][65];
    int tr = tid >> 4, tc = tid & 15;
#pragma unroll
    for (int rr = 0; rr < 4; ++rr) {
        int k = tr + rr*16;
        float4 v = *(const float4*)(W + (size_t)(kb + k)*N + nb + tc*4);
        tile[k][tc*4+0] = v.x; tile[k][tc*4+1] = v.y;
        tile[k][tc*4+2] = v.z; tile[k][tc*4+3] = v.w;
    }
    __syncthreads();
#pragma unroll
    for (int rr = 0; rr < 4; ++rr) {
        int n = tr + rr*16;
        ushort4 o;
        o.x = f2b(tile[tc*4+0][n]);
        o.y = f2b(tile[tc*4+1][n]);
        o.z = f2b(tile[tc*4+2][n]);
        o.w = f2b(tile[tc*4+3][n]);
        *(ushort4*)(Wt + (size_t)(nb + n)*K + kb + tc*4) = o;
    }
}

// generic single-matrix version (embed w2 weights)
__global__ __launch_bounds__(256) void tconv_kernel(const float* __restrict__ W,
                                                    u16* __restrict__ Wt,
                                                    int K, int N)
{
    tconv_tile(W, Wt, K, N, blockIdx.x*64, blockIdx.y*64, threadIdx.x);
}

// per-layer FUSED conversion of all weights (QKV, P, Wm1, Wm2): grid 3072 flat
__global__ __launch_bounds__(256) void tconvL_kernel(const float* __restrict__ Wq,
                                                     const float* __restrict__ Wk,
                                                     const float* __restrict__ Wv,
                                                     const float* __restrict__ Wp,
                                                     const float* __restrict__ Wm1,
                                                     const float* __restrict__ Wm2,
                                                     u16* __restrict__ Wqkvt,
                                                     u16* __restrict__ Wpt,
                                                     u16* __restrict__ Wm1t,
                                                     u16* __restrict__ Wm2t,
                                                     int layer)
{
    size_t DD = (size_t)D_*D_, DDF = (size_t)D_*DF_;
    int t = blockIdx.x;
    if (t < 1024) {
        int sel = t >> 8, tt = t & 255;
        const float* Wz = ((sel == 0) ? Wq : (sel == 1) ? Wk : (sel == 2) ? Wv : Wp) + layer*DD;
        u16* Wtz = (sel == 3) ? (Wpt + layer*DD) : (Wqkvt + layer*3*DD + sel*DD);
        tconv_tile(Wz, Wtz, D_, D_, (tt & 15)*64, (tt >> 4)*64, threadIdx.x);
    } else if (t < 2048) {
        int t2 = t - 1024;     // Wm1: K=D_, N=DF_; 64 n-tiles x 16 k-tiles
        tconv_tile(Wm1 + layer*DDF, Wm1t + layer*DDF, D_, DF_, (t2 & 63)*64, (t2 >> 6)*64, threadIdx.x);
    } else {
        int t2 = t - 2048;     // Wm2: K=DF_, N=D_; 16 n-tiles x 64 k-tiles
        tconv_tile(Wm2 + layer*DDF, Wm2t + layer*DDF, DF_, D_, (t2 & 15)*64, (t2 >> 4)*64, threadIdx.x);
    }
}

// bqkv[layer][3*1024] = concat(bq[layer], bk[layer], bv[layer])
__global__ __launch_bounds__(256) void pack_qkv_bias_kernel(const float* __restrict__ bq,
                                                            const float* __restrict__ bk,
                                                            const float* __restrict__ bv,
                                                            float* __restrict__ out)
{
    int i = blockIdx.x*256 + threadIdx.x;      // NL_*3072 = 18432 exactly
    int layer = i / 3072;
    int r = i - layer*3072;
    int c = r >> 10, d = r & 1023;
    const float* src = (c == 0) ? bq : (c == 1) ? bk : bv;
    out[i] = src[layer*1024 + d];
}

// lin_w (1024x27) -> lin_wT (27x1024) f32
__global__ __launch_bounds__(256) void tlin_kernel(const float* __restrict__ w,
                                                   float* __restrict__ wt)
{
    int k = blockIdx.x*256 + threadIdx.x;      // 1024
#pragma unroll 1
    for (int c = 0; c < 27; ++c)
        wt[c*1024 + k] = w[k*27 + c];
}

// ---------------------------------------------------------------------------
// Small VALU GEMM for the K=91 / K=27 embedding first layers (trivial FLOPs).
// ---------------------------------------------------------------------------
__global__ __launch_bounds__(256) void embed1_kernel(const float* __restrict__ A,
                                                     const float* __restrict__ W,
                                                     const float* __restrict__ bias,
                                                     u16* __restrict__ out, int K)
{
    int idx = blockIdx.x*256 + threadIdx.x;     // 1024*1024 outputs
    int m = idx >> 10, n = idx & 1023;
    float acc = bias[n];
    for (int k = 0; k < K; ++k)
        acc += A[m*K + k] * W[k*1024 + n];
    out[idx] = f2b(gelu_f(acc));
}

// ---------------------------------------------------------------------------
// rtg embedding
// ---------------------------------------------------------------------------
__global__ __launch_bounds__(128) void rtg_kernel(const float* __restrict__ rtgs,
                                                  const float* __restrict__ ret_w,
                                                  const float* __restrict__ res_w,
                                                  const float* __restrict__ bucket_w,
                                                  const float* __restrict__ bucket_b,
                                                  float* __restrict__ eR)
{
    int r = blockIdx.x, tid = threadIdx.x;
    __shared__ float sarr[NB_];
    __shared__ float red[128];
    float rtg = rtgs[r];
    float s = 0.f;
    if (tid < NB_) {
        float v = rtg * ret_w[tid];
        s = (v > 0.f) ? v : 0.01f*v;
        sarr[tid] = s;
    }
    __syncthreads();
    float s2 = -1e30f;
    if (tid < NB_) {
        float acc = s;
        for (int m = 0; m < NB_; ++m) acc += sarr[m] * res_w[m*NB_ + tid];
        s2 = acc;
    }
    red[tid] = s2; __syncthreads();
    for (int off = 64; off > 0; off >>= 1) { if (tid < off) red[tid] = fmaxf(red[tid], red[tid+off]); __syncthreads(); }
    float mx = red[0]; __syncthreads();
    float e = (tid < NB_) ? expf(s2 - mx) : 0.f;
    red[tid] = e; __syncthreads();
    for (int off = 64; off > 0; off >>= 1) { if (tid < off) red[tid] += red[tid+off]; __syncthreads(); }
    float S = red[0]; __syncthreads();
    float bv = (100.f/99.f) * (float)tid;
    red[tid] = e * bv; __syncthreads();
    for (int off = 64; off > 0; off >>= 1) { if (tid < off) red[tid] += red[tid+off]; __syncthreads(); }
    float EB = red[0];
    float inv = 1.f/(1e-8f + S);
    float c = EB * inv, sg = S * inv;
    for (int d = tid; d < D_; d += 128)
        eR[(size_t)r*D_ + d] = c*bucket_w[d] + sg*bucket_b[d];
}

// ---------------------------------------------------------------------------
// assemble: x[b,3l+c,:] = emb_c[b,l,:] + pos[3l+c,:]   (f32 stream)
// ---------------------------------------------------------------------------
__global__ __launch_bounds__(256) void assemble_kernel(const float* __restrict__ eR,
                                                       const float* __restrict__ eS,
                                                       const float* __restrict__ eA,
                                                       const float* __restrict__ pos,
                                                       float* __restrict__ xf)
{
    int idx = blockIdx.x*256 + threadIdx.x;       // BT_*D_
    int row = idx >> 10, d = idx & 1023;
    int b = row / T_, t = row % T_;
    int l = t / 3, c = t % 3;
    const float* src = (c == 0) ? eR : (c == 1) ? eS : eA;
    xf[idx] = src[(size_t)(b*L_ + l)*D_ + d] + pos[(size_t)t*D_ + d];
}

// ---------------------------------------------------------------------------
// LayerNorm, wave-per-row (4 rows/block, no LDS, no barriers).
// NP=4: row = x + sum of 4 split-K partial slabs; summed row written to xout.
// ---------------------------------------------------------------------------
template<int NP>
__global__ __launch_bounds__(256) void ln_kernel(const float* __restrict__ x,
                                                 const float* __restrict__ parts,
                                                 size_t pstride,
                                                 const float* __restrict__ g,
                                                 const float* __restrict__ bb,
                                                 float* __restrict__ xout,
                                                 u16* __restrict__ out)
{
    int row = blockIdx.x*4 + (threadIdx.x >> 6);
    int lane = threadIdx.x & 63;
    const float4* xr = (const float4*)(x + (size_t)row*D_);
    float4 v[4];
    float s = 0.f, q = 0.f;
#pragma unroll
    for (int i = 0; i < 4; ++i) {
        float4 a = xr[lane + i*64];
        if (NP == 4) {
#pragma unroll
            for (int z = 0; z < 4; ++z) {
                float4 p = ((const float4*)(parts + (size_t)z*pstride + (size_t)row*D_))[lane + i*64];
                a.x += p.x; a.y += p.y; a.z += p.z; a.w += p.w;
            }
        }
        v[i] = a;
        s += a.x+a.y+a.z+a.w;
        q += a.x*a.x+a.y*a.y+a.z*a.z+a.w*a.w;
    }
    if (NP == 4) {
#pragma unroll
        for (int i = 0; i < 4; ++i)
            ((float4*)(xout + (size_t)row*D_))[lane + i*64] = v[i];
    }
#pragma unroll
    for (int off = 1; off < 64; off <<= 1) {
        s += __shfl_xor(s, off, 64);
        q += __shfl_xor(q, off, 64);
    }
    float mean = s*(1.f/(float)D_);
    float var  = q*(1.f/(float)D_) - mean*mean;
    float rstd = rsqrtf(var + 1e-5f);
#pragma unroll
    for (int i = 0; i < 4; ++i) {
        int d0 = (lane + i*64)*4;
        ushort4 ov;
        ov.x = f2b((v[i].x-mean)*rstd*g[d0+0] + bb[d0+0]);
        ov.y = f2b((v[i].y-mean)*rstd*g[d0+1] + bb[d0+1]);
        ov.z = f2b((v[i].z-mean)*rstd*g[d0+2] + bb[d0+2]);
        ov.w = f2b((v[i].w-mean)*rstd*g[d0+3] + bb[d0+3]);
        ((ushort4*)(out + (size_t)row*D_))[lane + i*64] = ov;
    }
}

// ---------------------------------------------------------------------------
// MFMA bf16 GEMM: C(MxN) = act(A(MxK) @ Wt(NxK)^T + bias).
// 128x128 tile / 4 waves / BK=32 / 16x16x32 MFMA. 3-slab counted-vmcnt pipe.
// SPLITK>1: blockIdx.z owns K-chunk kc; ATOMIC ? atomicAdd into outF
// : plain store to outF + z*partStride (reduced later in fused LN).
// ---------------------------------------------------------------------------
template<int GELU_ACT, int SPLITK, int ATOMIC>
__global__ __launch_bounds__(256) void gemm_bt(const u16* __restrict__ A,
                                               const u16* __restrict__ Bt,
                                               const float* __restrict__ bias,
                                               float* __restrict__ outF,
                                               u16* __restrict__ outB,
                                               int M, int N, int K, int kc,
                                               size_t partStride)
{
    __shared__ __align__(16) u16 As[3*128*32];
    __shared__ __align__(16) u16 Bs[3*128*32];
    int tid = threadIdx.x;

    int gx = gridDim.x;
    int nwg = gx * gridDim.y;
    int id = blockIdx.y * gx + blockIdx.x;
    int q8 = nwg >> 3;                         // nwg % 8 == 0 for all launches
    int nid = (id & 7) * q8 + (id >> 3);       // contiguous tile range per XCD
    int n0 = (nid % gx) * 128;
    int m0 = (nid / gx) * 128;

    int wave = tid >> 6, lane = tid & 63;
    int wm = (wave >> 1) * 64, wn = (wave & 1) * 64;
    int lr = lane & 15, lq = lane >> 4;
    int slotRd = (lq ^ ((lr >> 1) & 3)) * 8;   // swizzled k-slot (u16 units)

    int srow = tid >> 2;                       // staging row 0..63 (+64)
    int sslot = (tid & 3) ^ ((srow >> 1) & 3); // swizzled source col-block

    int k0 = (SPLITK > 1) ? blockIdx.z * kc : 0;
    int nIt = ((SPLITK > 1) ? kc : K) >> 5;

    const u16* ap0 = A  + (size_t)(m0 + srow) * K + k0 + sslot * 8;
    const u16* ap1 = ap0 + (size_t)64 * K;
    const u16* bp0 = Bt + (size_t)(n0 + srow) * K + k0 + sslot * 8;
    const u16* bp1 = bp0 + (size_t)64 * K;

    // slab base pointers (rotate each iteration; reads from sA0, stage into sA2)
    u16 *sA0 = As, *sA1 = As + 4096, *sA2 = As + 8192;
    u16 *sB0 = Bs, *sB1 = Bs + 4096, *sB2 = Bs + 8192;
    int woff = wave * 512;

    f32x4 acc[4][4];
#pragma unroll
    for (int i = 0; i < 4; ++i)
#pragma unroll
        for (int j = 0; j < 4; ++j) acc[i][j] = (f32x4){0.f,0.f,0.f,0.f};

    // prologue: stage tiles 0 and 1 (order matters for vmcnt counting)
    gload16(ap0, sA0 + woff); gload16(ap1, sA0 + 2048 + woff);
    gload16(bp0, sB0 + woff); gload16(bp1, sB0 + 2048 + woff);
    ap0 += 32; ap1 += 32; bp0 += 32; bp1 += 32;
    gload16(ap0, sA1 + woff); gload16(ap1, sA1 + 2048 + woff);
    gload16(bp0, sB1 + woff); gload16(bp1, sB1 + 2048 + woff);
    ap0 += 32; ap1 += 32; bp0 += 32; bp1 += 32;

    for (int it = 0; it < nIt; ++it) {
        if (it + 1 < nIt) asm volatile("s_waitcnt vmcnt(4)" ::: "memory");
        else              asm volatile("s_waitcnt vmcnt(0)" ::: "memory");
        asm volatile("s_barrier" ::: "memory");
        if (it + 2 < nIt) {                    // stage tile t+2 into slab2
            gload16(ap0, sA2 + woff); gload16(ap1, sA2 + 2048 + woff);
            gload16(bp0, sB2 + woff); gload16(bp1, sB2 + 2048 + woff);
            ap0 += 32; ap1 += 32; bp0 += 32; bp1 += 32;
        }
        s16x8 af[4], bf[4];
#pragma unroll
        for (int i = 0; i < 4; ++i)
            af[i] = *(const s16x8*)(sA0 + (wm + i*16 + lr)*32 + slotRd);
#pragma unroll
        for (int j = 0; j < 4; ++j)
            bf[j] = *(const s16x8*)(sB0 + (wn + j*16 + lr)*32 + slotRd);
#pragma unroll
        for (int i = 0; i < 4; ++i)
#pragma unroll
            for (int j = 0; j < 4; ++j)
                acc[i][j] = __builtin_amdgcn_mfma_f32_16x16x32_bf16(af[i], bf[j], acc[i][j], 0, 0, 0);
        // rotate slabs: t+1 becomes current, freed slab becomes stage target
        u16* t0 = sA0; sA0 = sA1; sA1 = sA2; sA2 = t0;
        u16* t1 = sB0; sB0 = sB1; sB1 = sB2; sB2 = t1;
    }

    float* outZ = (SPLITK > 1 && !ATOMIC) ? outF + (size_t)blockIdx.z * partStride : outF;
#pragma unroll
    for (int i = 0; i < 4; ++i) {
        int mbase = m0 + wm + i*16 + lq*4;
#pragma unroll
        for (int j = 0; j < 4; ++j) {
            int n = n0 + wn + j*16 + lr;
            float bvl = (SPLITK > 1) ? ((blockIdx.z == 0) ? bias[n] : 0.f) : bias[n];
#pragma unroll
            for (int r = 0; r < 4; ++r) {
                int m = mbase + r;
                float v = acc[i][j][r] + bvl;
                size_t off = (size_t)m*N + n;
                if (SPLITK > 1) {
                    if (ATOMIC) atomicAdd(outF + off, v);
                    else        outZ[off] = v;
                } else {
                    if (GELU_ACT) v = gelu_f(v);
                    if (outF) outF[off] = v;
                    if (outB) outB[off] = f2b(v);
                }
            }
        }
    }
}

// ---------------------------------------------------------------------------
// MFMA flash-style attention. Grid (B*H, 3): blockIdx.y = causal chunk c;
// block handles q-tiles c*4+w (one per wave). K is NOT staged (L2/L3-hot
// after the QKV GEMM) -- B-fragments read straight from global. Only V
// (transposed) + per-wave P chunks in LDS: 31 KB -> 5 blocks/CU. Single
// barrier placed AFTER QK^T/softmax so V-staging hides under compute.
// ---------------------------------------------------------------------------
__global__ __launch_bounds__(256) void attn_mfma_kernel(const u16* __restrict__ qkv,
                                                        u16* __restrict__ yb)
{
    __shared__ __align__(16) u16 Vt[64*200];
    __shared__ __align__(16) u16 Pch[4][16*40];

    int tid = threadIdx.x;
    int b = blockIdx.x >> 4, h = blockIdx.x & 15;
    int c = blockIdx.y;
    int nrows = (c + 1) * 64;
    int bT = b * T_;
    int colBase = h * 64;
    int w = tid >> 6, lane = tid & 63;
    int lr = lane & 15, lq = lane >> 4;
    const int S3 = 3 * D_;

    // stage V (transposed), rows [0, nrows)
    for (int it = 0; it < (nrows >> 5); ++it) {
        int cc = it*256 + tid;
        int row = cc >> 3, ch = cc & 7;
        union { int4 v; u16 s[8]; } rv;
        rv.v = *(const int4*)(qkv + (size_t)(bT+row)*S3 + 2*D_ + colBase + ch*8);
#pragma unroll
        for (int i2 = 0; i2 < 8; ++i2)
            Vt[(ch*8 + i2)*200 + row] = rv.s[i2];
    }

    u16* Ch = Pch[w];
    int qt = c*4 + w;                 // this wave's q-tile (0..11)
    int tqb = qt * 16;

    // Q A-fragments (global, L2-hot)
    const u16* qrow = qkv + (size_t)(bT + tqb + lr)*S3 + colBase + lq*8;
    s16x8 af0 = *(const s16x8*)(qrow);
    s16x8 af1 = *(const s16x8*)(qrow + 32);

    // S = Q K^T  (K B-fragments from global/L2; C layout: row=lq*4+r, col=lr)
    f32x4 sacc[12];
#pragma unroll
    for (int jt = 0; jt < 12; ++jt) {
        if (jt <= qt) {
            const u16* kr = qkv + (size_t)(bT + jt*16 + lr)*S3 + D_ + colBase + lq*8;
            s16x8 bk0 = *(const s16x8*)(kr);
            s16x8 bk1 = *(const s16x8*)(kr + 32);
            f32x4 a = (f32x4){0.f,0.f,0.f,0.f};
            a = __builtin_amdgcn_mfma_f32_16x16x32_bf16(af0, bk0, a, 0, 0, 0);
            a = __builtin_amdgcn_mfma_f32_16x16x32_bf16(af1, bk1, a, 0, 0, 0);
            sacc[jt] = a;
        }
    }

    // mask + row max
    float mrow[4] = {-1e30f,-1e30f,-1e30f,-1e30f};
#pragma unroll
    for (int jt = 0; jt < 12; ++jt) if (jt <= qt) {
#pragma unroll
        for (int r = 0; r < 4; ++r) {
            bool valid = (jt < qt) || (lr <= lq*4 + r);
            float s = valid ? sacc[jt][r]*0.125f : -1e30f;
            sacc[jt][r] = s;
            mrow[r] = fmaxf(mrow[r], s);
        }
    }
#pragma unroll
    for (int r = 0; r < 4; ++r) {
#pragma unroll
        for (int off = 1; off < 16; off <<= 1)
            mrow[r] = fmaxf(mrow[r], __shfl_xor(mrow[r], off, 64));
    }

    // exp + row sum (e kept in sacc registers)
    float lrow[4] = {0.f,0.f,0.f,0.f};
#pragma unroll
    for (int jt = 0; jt < 12; ++jt) if (jt <= qt) {
#pragma unroll
        for (int r = 0; r < 4; ++r) {
            float e = __expf(sacc[jt][r] - mrow[r]);
            sacc[jt][r] = e;
            lrow[r] += e;
        }
    }
#pragma unroll
    for (int r = 0; r < 4; ++r) {
#pragma unroll
        for (int off = 1; off < 16; off <<= 1)
            lrow[r] += __shfl_xor(lrow[r], off, 64);
        lrow[r] = 1.f / lrow[r];
    }

    __syncthreads();                  // V staged (hidden under QK^T+softmax)

    // PV: per 32-key chunk, write P chunk (C->A layout via LDS), mfma
    int nkt = (qt + 2) >> 1;
    f32x4 oacc[4];
#pragma unroll
    for (int nt = 0; nt < 4; ++nt) oacc[nt] = (f32x4){0.f,0.f,0.f,0.f};

#pragma unroll
    for (int kt = 0; kt < 6; ++kt) if (kt < nkt) {
        int jt0 = 2*kt, jt1 = 2*kt + 1;
#pragma unroll
        for (int r = 0; r < 4; ++r) {
            u16 e0 = f2b(sacc[jt0][r]);
            u16 e1 = (jt1 <= qt) ? f2b(sacc[jt1][r]) : (u16)0;
            Ch[(lq*4 + r)*40 + lr]      = e0;
            Ch[(lq*4 + r)*40 + 16 + lr] = e1;
        }
        s16x8 ap = *(const s16x8*)(Ch + lr*40 + lq*8);
#pragma unroll
        for (int nt = 0; nt < 4; ++nt) {
            s16x8 bv = *(const s16x8*)(Vt + (nt*16 + lr)*200 + kt*32 + lq*8);
            oacc[nt] = __builtin_amdgcn_mfma_f32_16x16x32_bf16(ap, bv, oacc[nt], 0, 0, 0);
        }
    }

    // store O (C layout), normalized by 1/l
#pragma unroll
    for (int nt = 0; nt < 4; ++nt)
#pragma unroll
        for (int r = 0; r < 4; ++r)
            yb[(size_t)(bT + tqb + lq*4 + r)*D_ + colBase + nt*16 + lr] =
                f2b(oacc[nt][r] * lrow[r]);
}

// ---------------------------------------------------------------------------
// Final linear: out(BT x 27) = (xf [+4 partials]) @ lin_wT^T + lin_b.
// One wave per row; shuffle reduce per output column.
// ---------------------------------------------------------------------------
template<int NP>
__global__ __launch_bounds__(256) void final_kernel(const float* __restrict__ xf,
                                                    const float* __restrict__ parts,
                                                    size_t pstride,
                                                    const float* __restrict__ lin_wT,
                                                    const float* __restrict__ lin_b,
                                                    float* __restrict__ out)
{
    int row = blockIdx.x*4 + (threadIdx.x >> 6);
    int lane = threadIdx.x & 63;
    const float4* xr = (const float4*)(xf + (size_t)row*D_);
    float4 x[4];
#pragma unroll
    for (int i = 0; i < 4; ++i) {
        float4 v = xr[lane + i*64];
        if (NP == 4) {
#pragma unroll
            for (int z = 0; z < 4; ++z) {
                float4 p = ((const float4*)(parts + (size_t)z*pstride + (size_t)row*D_))[lane + i*64];
                v.x += p.x; v.y += p.y; v.z += p.z; v.w += p.w;
            }
        }
        x[i] = v;
    }
#pragma unroll 1
    for (int c = 0; c < 27; ++c) {
        const float4* wr = (const float4*)(lin_wT + (size_t)c*D_);
        float a = 0.f;
#pragma unroll
        for (int i = 0; i < 4; ++i) {
            float4 wv = wr[lane + i*64];
            a += x[i].x*wv.x + x[i].y*wv.y + x[i].z*wv.z + x[i].w*wv.w;
        }
#pragma unroll
        for (int off = 1; off < 64; off <<= 1)
            a += __shfl_xor(a, off, 64);
        if (lane == 0) out[(size_t)row*27 + c] = a + lin_b[c];
    }
}

// ---------------------------------------------------------------------------
extern "C" void kernel_launch(void* const* d_in, const int* in_sizes, int n_in,
                              void* d_out, int out_size, void* d_ws, size_t ws_size,
                              hipStream_t stream)
{
    const float* states   = (const float*)d_in[0];
    const float* actions  = (const float*)d_in[1];
    const float* rtgs     = (const float*)d_in[2];
    const float* se_w1 = (const float*)d_in[5];
    const float* se_b1 = (const float*)d_in[6];
    const float* se_w2 = (const float*)d_in[7];
    const float* se_b2 = (const float*)d_in[8];
    const float* ae_w1 = (const float*)d_in[9];
    const float* ae_b1 = (const float*)d_in[10];
    const float* ae_w2 = (const float*)d_in[11];
    const float* ae_b2 = (const float*)d_in[12];
    const float* ad_bucket_w = (const float*)d_in[13];
    const float* ad_bucket_b = (const float*)d_in[14];
    const float* ad_ret_w = (const float*)d_in[15];
    const float* ad_res_w = (const float*)d_in[16];
    const float* pos_emb  = (const float*)d_in[17];
    const float* ln1_g = (const float*)d_in[18];
    const float* ln1_b = (const float*)d_in[19];
    const float* Wq = (const float*)d_in[20];
    const float* bq = (const float*)d_in[21];
    const float* Wk = (const float*)d_in[22];
    const float* bk = (const float*)d_in[23];
    const float* Wv = (const float*)d_in[24];
    const float* bv = (const float*)d_in[25];
    const float* Wp = (const float*)d_in[26];
    const float* bp = (const float*)d_in[27];
    const float* ln2_g = (const float*)d_in[28];
    const float* ln2_b = (const float*)d_in[29];
    const float* Wm1 = (const float*)d_in[30];
    const float* bm1 = (const float*)d_in[31];
    const float* Wm2 = (const float*)d_in[32];
    const float* bm2 = (const float*)d_in[33];
    const float* lin_w = (const float*)d_in[34];
    const float* lin_b = (const float*)d_in[35];

    char* w = (char*)d_ws;
    auto take = [&](size_t bytes) { char* p = w; w += (bytes + 255) & ~(size_t)255; return p; };

    float* xf   = (float*)take((size_t)BT_*D_*4);
    u16* hb     = (u16*)take((size_t)BT_*D_*2);        // ln out; also attn-y
    u16* qkvb   = (u16*)take((size_t)BT_*3*D_*2);      // fused QKV bf16
    char* scr   =        take((size_t)BT_*DF_*2);      // midb; embed scratch aliased
    u16*  midb  = (u16*)scr;
    u16*  tSb   = (u16*)scr;
    u16*  tAb   = (u16*)(scr + (size_t)BL_*D_*2);
    float* eS   = (float*)(scr + (size_t)2*BL_*D_*2);
    float* eA   = (float*)(scr + (size_t)2*BL_*D_*2 + (size_t)BL_*D_*4);
    float* eR   = (float*)(scr + (size_t)2*BL_*D_*2 + (size_t)2*BL_*D_*4);
    float* pp   = (float*)take((size_t)4*BT_*D_*4);    // P-projection partials (4 slabs)
    float* mq   = (float*)take((size_t)4*BT_*D_*4);    // MLP2 partials (4 slabs)

    // pre-transposed bf16 weights (N x K)
    u16* Wqkvt = (u16*)take((size_t)NL_*3*D_*D_*2);
    u16* Wpt   = (u16*)take((size_t)NL_*D_*D_*2);
    u16* Wm1t  = (u16*)take((size_t)NL_*D_*DF_*2);
    u16* Wm2t  = (u16*)take((size_t)NL_*DF_*D_*2);
    u16* sw2t  = (u16*)take((size_t)D_*D_*2);
    u16* aw2t  = (u16*)take((size_t)D_*D_*2);
    float* bqkv= (float*)take((size_t)NL_*3*D_*4);
    float* lwT = (float*)take((size_t)27*D_*4);

    size_t ask = (size_t)(w - (char*)d_ws);
    bool bigWS = (ws_size >= ask);   // slabs available?
    // (if not, P/MLP2 fall back to atomic split-K into xf; LNs/final use NP=0)

    const size_t PSTRIDE = (size_t)BT_*D_;
    size_t DD = (size_t)D_*D_, DDF = (size_t)D_*DF_;

    // --- small prep + layer-0 weights (JIT: layer i+1 converted during layer i) ---
    pack_qkv_bias_kernel<<<72, 256, 0, stream>>>(bq, bk, bv, bqkv);
    tlin_kernel<<<4, 256, 0, stream>>>(lin_w, lwT);
    tconv_kernel<<<dim3(16,16), 256, 0, stream>>>(se_w2, sw2t, D_, D_);
    tconv_kernel<<<dim3(16,16), 256, 0, stream>>>(ae_w2, aw2t, D_, D_);
    tconvL_kernel<<<3072, 256, 0, stream>>>(Wq, Wk, Wv, Wp, Wm1, Wm2,
                                            Wqkvt, Wpt, Wm1t, Wm2t, 0);

    // --- embeddings ---
    embed1_kernel<<<4096, 256, 0, stream>>>(states,  se_w1, se_b1, tSb, 91);
    embed1_kernel<<<4096, 256, 0, stream>>>(actions, ae_w1, ae_b1, tAb, 27);
    gemm_bt<1,1,0><<<dim3(8,8), 256, 0, stream>>>(tSb, sw2t, se_b2, eS, nullptr, BL_, D_, D_, D_, 0);
    gemm_bt<0,1,0><<<dim3(8,8), 256, 0, stream>>>(tAb, aw2t, ae_b2, eA, nullptr, BL_, D_, D_, D_, 0);
    rtg_kernel<<<BL_, 128, 0, stream>>>(rtgs, ad_ret_w, ad_res_w, ad_bucket_w, ad_bucket_b, eR);
    assemble_kernel<<<(BT_*D_)/256, 256, 0, stream>>>(eR, eS, eA, pos_emb, xf);

    // --- transformer layers ---
    for (int i = 0; i < NL_; ++i) {
        // ln1: layers >0 also reduce the previous MLP2 partials into xf
        if (i > 0 && bigWS)
            ln_kernel<4><<<BT_/4, 256, 0, stream>>>(xf, mq, PSTRIDE, ln1_g + i*D_, ln1_b + i*D_, xf, hb);
        else
            ln_kernel<0><<<BT_/4, 256, 0, stream>>>(xf, nullptr, 0, ln1_g + i*D_, ln1_b + i*D_, nullptr, hb);
        // fused QKV
        gemm_bt<0,1,0><<<dim3(24,24), 256, 0, stream>>>(hb, Wqkvt + (size_t)i*3*DD, bqkv + i*3*D_,
                                                        nullptr, qkvb, BT_, 3*D_, D_, D_, 0);
        attn_mfma_kernel<<<dim3(B_*H_,3), 256, 0, stream>>>(qkvb, hb);   // y -> hb
        // JIT: convert next layer's weights now (L2/L3-hot when used)
        if (i + 1 < NL_)
            tconvL_kernel<<<3072, 256, 0, stream>>>(Wq, Wk, Wv, Wp, Wm1, Wm2,
                                                    Wqkvt, Wpt, Wm1t, Wm2t, i+1);
        // P projection: split-K x4 into slabs (768 blocks = 3/CU)
        if (bigWS)
            gemm_bt<0,4,0><<<dim3(8,24,4), 256, 0, stream>>>(hb, Wpt + (size_t)i*DD, bp + i*D_,
                                                             pp, nullptr, BT_, D_, D_, 256, PSTRIDE);
        else
            gemm_bt<0,2,1><<<dim3(8,24,2), 256, 0, stream>>>(hb, Wpt + (size_t)i*DD, bp + i*D_,
                                                             xf, nullptr, BT_, D_, D_, 512, 0);
        // ln2 reduces P partials, updates xf, emits bf16 LN
        if (bigWS)
            ln_kernel<4><<<BT_/4, 256, 0, stream>>>(xf, pp, PSTRIDE, ln2_g + i*D_, ln2_b + i*D_, xf, hb);
        else
            ln_kernel<0><<<BT_/4, 256, 0, stream>>>(xf, nullptr, 0, ln2_g + i*D_, ln2_b + i*D_, nullptr, hb);
        // MLP
        gemm_bt<1,1,0><<<dim3(32,24), 256, 0, stream>>>(hb, Wm1t + (size_t)i*DDF, bm1 + i*DF_,
                                                        nullptr, midb, BT_, DF_, D_, D_, 0);
        if (bigWS)
            gemm_bt<0,4,0><<<dim3(8,24,4), 256, 0, stream>>>(midb, Wm2t + (size_t)i*DDF, bm2 + i*D_,
                                                             mq, nullptr, BT_, D_, DF_, 1024, PSTRIDE);
        else
            gemm_bt<0,2,1><<<dim3(8,24,2), 256, 0, stream>>>(midb, Wm2t + (size_t)i*DDF, bm2 + i*D_,
                                                             xf, nullptr, BT_, D_, DF_, 2048, 0);
    }

    // --- head (reduces last MLP2 partials on the fly) ---
    if (bigWS)
        final_kernel<4><<<BT_/4, 256, 0, stream>>>(xf, mq, PSTRIDE, lwT, lin_b, (float*)d_out);
    else
        final_kernel<0><<<BT_/4, 256, 0, stream>>>(xf, nullptr, 0, lwT, lin_b, (float*)d_out);
}

// Round 7
// 1489.242 us; speedup vs baseline: 1.0764x; 1.0456x over previous
//
#include <hip/hip_runtime.h>
#include <cmath>

typedef unsigned short u16;
typedef unsigned int   u32;
typedef short s16x8 __attribute__((ext_vector_type(8)));
typedef float f32x4 __attribute__((ext_vector_type(4)));

#define D_  1024
#define H_  16
#define NL_ 6
#define B_  16
#define L_  64
#define T_  192
#define NB_ 100
#define DF_ 4096
#define BT_ (B_*T_)   /* 3072 rows in stream */
#define BL_ (B_*L_)   /* 1024 rows per modality */

__device__ __forceinline__ float b2f(u16 u){ u32 x = ((u32)u)<<16; return __uint_as_float(x); }
__device__ __forceinline__ u16 f2b(float f){ u32 x = __float_as_uint(f); x += 0x7fffu + ((x>>16)&1u); return (u16)(x>>16); }
__device__ __forceinline__ float gelu_f(float v){ return 0.5f*v*(1.0f+erff(v*0.70710678118f)); }

// async global->LDS, 16B per lane. LDS dest is wave-uniform base + lane*16.
typedef const unsigned int __attribute__((address_space(1)))* as1_u32p;
typedef unsigned int __attribute__((address_space(3)))* as3_u32p;
__device__ __forceinline__ void gload16(const void* g, void* l)
{
    __builtin_amdgcn_global_load_lds((as1_u32p)g, (as3_u32p)l, 16, 0, 0);
}

// ---------------------------------------------------------------------------
// Transpose + f32->bf16 convert core: W[K][N] f32 -> Wt[N][K] bf16, 64x64 tile
// ---------------------------------------------------------------------------
__device__ __forceinline__ void tconv_tile(const float* __restrict__ W,
                                           u16* __restrict__ Wt,
                                           int K, int N, int nb, int kb, int tid)
{
    __shared__ float tile[64][65];
    int tr = tid >> 4, tc = tid & 15;
#pragma unroll
    for (int rr = 0; rr < 4; ++rr) {
        int k = tr + rr*16;
        float4 v = *(const float4*)(W + (size_t)(kb + k)*N + nb + tc*4);
        tile[k][tc*4+0] = v.x; tile[k][tc*4+1] = v.y;
        tile[k][tc*4+2] = v.z; tile[k][tc*4+3] = v.w;
    }
    __syncthreads();
#pragma unroll
    for (int rr = 0; rr < 4; ++rr) {
        int n = tr + rr*16;
        ushort4 o;
        o.x = f2b(tile[tc*4+0][n]);
        o.y = f2b(tile[tc*4+1][n]);
        o.z = f2b(tile[tc*4+2][n]);
        o.w = f2b(tile[tc*4+3][n]);
        *(ushort4*)(Wt + (size_t)(nb + n)*K + kb + tc*4) = o;
    }
}

// generic single-matrix version (embed w2 weights)
__global__ __launch_bounds__(256) void tconv_kernel(const float* __restrict__ W,
                                                    u16* __restrict__ Wt,
                                                    int K, int N)
{
    tconv_tile(W, Wt, K, N, blockIdx.x*64, blockIdx.y*64, threadIdx.x);
}

// per-layer FUSED conversion of all weights (QKV, P, Wm1, Wm2): grid 3072 flat
__global__ __launch_bounds__(256) void tconvL_kernel(const float* __restrict__ Wq,
                                                     const float* __restrict__ Wk,
                                                     const float* __restrict__ Wv,
                                                     const float* __restrict__ Wp,
                                                     const float* __restrict__ Wm1,
                                                     const float* __restrict__ Wm2,
                                                     u16* __restrict__ Wqkvt,
                                                     u16* __restrict__ Wpt,
                                                     u16* __restrict__ Wm1t,
                                                     u16* __restrict__ Wm2t,
                                                     int layer)
{
    size_t DD = (size_t)D_*D_, DDF = (size_t)D_*DF_;
    int t = blockIdx.x;
    if (t < 1024) {
        int sel = t >> 8, tt = t & 255;
        const float* Wz = ((sel == 0) ? Wq : (sel == 1) ? Wk : (sel == 2) ? Wv : Wp) + layer*DD;
        u16* Wtz = (sel == 3) ? (Wpt + layer*DD) : (Wqkvt + layer*3*DD + sel*DD);
        tconv_tile(Wz, Wtz, D_, D_, (tt & 15)*64, (tt >> 4)*64, threadIdx.x);
    } else if (t < 2048) {
        int t2 = t - 1024;     // Wm1: K=D_, N=DF_; 64 n-tiles x 16 k-tiles
        tconv_tile(Wm1 + layer*DDF, Wm1t + layer*DDF, D_, DF_, (t2 & 63)*64, (t2 >> 6)*64, threadIdx.x);
    } else {
        int t2 = t - 2048;     // Wm2: K=DF_, N=D_; 16 n-tiles x 64 k-tiles
        tconv_tile(Wm2 + layer*DDF, Wm2t + layer*DDF, DF_, D_, (t2 & 15)*64, (t2 >> 4)*64, threadIdx.x);
    }
}

// bqkv[layer][3*1024] = concat(bq[layer], bk[layer], bv[layer])
__global__ __launch_bounds__(256) void pack_qkv_bias_kernel(const float* __restrict__ bq,
                                                            const float* __restrict__ bk,
                                                            const float* __restrict__ bv,
                                                            float* __restrict__ out)
{
    int i = blockIdx.x*256 + threadIdx.x;      // NL_*3072 = 18432 exactly
    int layer = i / 3072;
    int r = i - layer*3072;
    int c = r >> 10, d = r & 1023;
    const float* src = (c == 0) ? bq : (c == 1) ? bk : bv;
    out[i] = src[layer*1024 + d];
}

// lin_w (1024x27) -> lin_wT (27x1024) f32
__global__ __launch_bounds__(256) void tlin_kernel(const float* __restrict__ w,
                                                   float* __restrict__ wt)
{
    int k = blockIdx.x*256 + threadIdx.x;      // 1024
#pragma unroll 1
    for (int c = 0; c < 27; ++c)
        wt[c*1024 + k] = w[k*27 + c];
}

// ---------------------------------------------------------------------------
// Small VALU GEMM for the K=91 / K=27 embedding first layers (trivial FLOPs).
// ---------------------------------------------------------------------------
__global__ __launch_bounds__(256) void embed1_kernel(const float* __restrict__ A,
                                                     const float* __restrict__ W,
                                                     const float* __restrict__ bias,
                                                     u16* __restrict__ out, int K)
{
    int idx = blockIdx.x*256 + threadIdx.x;     // 1024*1024 outputs
    int m = idx >> 10, n = idx & 1023;
    float acc = bias[n];
    for (int k = 0; k < K; ++k)
        acc += A[m*K + k] * W[k*1024 + n];
    out[idx] = f2b(gelu_f(acc));
}

// ---------------------------------------------------------------------------
// rtg embedding
// ---------------------------------------------------------------------------
__global__ __launch_bounds__(128) void rtg_kernel(const float* __restrict__ rtgs,
                                                  const float* __restrict__ ret_w,
                                                  const float* __restrict__ res_w,
                                                  const float* __restrict__ bucket_w,
                                                  const float* __restrict__ bucket_b,
                                                  float* __restrict__ eR)
{
    int r = blockIdx.x, tid = threadIdx.x;
    __shared__ float sarr[NB_];
    __shared__ float red[128];
    float rtg = rtgs[r];
    float s = 0.f;
    if (tid < NB_) {
        float v = rtg * ret_w[tid];
        s = (v > 0.f) ? v : 0.01f*v;
        sarr[tid] = s;
    }
    __syncthreads();
    float s2 = -1e30f;
    if (tid < NB_) {
        float acc = s;
        for (int m = 0; m < NB_; ++m) acc += sarr[m] * res_w[m*NB_ + tid];
        s2 = acc;
    }
    red[tid] = s2; __syncthreads();
    for (int off = 64; off > 0; off >>= 1) { if (tid < off) red[tid] = fmaxf(red[tid], red[tid+off]); __syncthreads(); }
    float mx = red[0]; __syncthreads();
    float e = (tid < NB_) ? expf(s2 - mx) : 0.f;
    red[tid] = e; __syncthreads();
    for (int off = 64; off > 0; off >>= 1) { if (tid < off) red[tid] += red[tid+off]; __syncthreads(); }
    float S = red[0]; __syncthreads();
    float bv = (100.f/99.f) * (float)tid;
    red[tid] = e * bv; __syncthreads();
    for (int off = 64; off > 0; off >>= 1) { if (tid < off) red[tid] += red[tid+off]; __syncthreads(); }
    float EB = red[0];
    float inv = 1.f/(1e-8f + S);
    float c = EB * inv, sg = S * inv;
    for (int d = tid; d < D_; d += 128)
        eR[(size_t)r*D_ + d] = c*bucket_w[d] + sg*bucket_b[d];
}

// ---------------------------------------------------------------------------
// assemble: x[b,3l+c,:] = emb_c[b,l,:] + pos[3l+c,:]   (f32 stream)
// ---------------------------------------------------------------------------
__global__ __launch_bounds__(256) void assemble_kernel(const float* __restrict__ eR,
                                                       const float* __restrict__ eS,
                                                       const float* __restrict__ eA,
                                                       const float* __restrict__ pos,
                                                       float* __restrict__ xf)
{
    int idx = blockIdx.x*256 + threadIdx.x;       // BT_*D_
    int row = idx >> 10, d = idx & 1023;
    int b = row / T_, t = row % T_;
    int l = t / 3, c = t % 3;
    const float* src = (c == 0) ? eR : (c == 1) ? eS : eA;
    xf[idx] = src[(size_t)(b*L_ + l)*D_ + d] + pos[(size_t)t*D_ + d];
}

// ---------------------------------------------------------------------------
// LayerNorm, wave-per-row (4 rows/block, no LDS, no barriers).
// NP=4: row = x + sum of 4 bf16 split-K partial slabs; summed row -> xout.
// ---------------------------------------------------------------------------
template<int NP>
__global__ __launch_bounds__(256) void ln_kernel(const float* __restrict__ x,
                                                 const u16* __restrict__ parts,
                                                 size_t pstride,
                                                 const float* __restrict__ g,
                                                 const float* __restrict__ bb,
                                                 float* __restrict__ xout,
                                                 u16* __restrict__ out)
{
    int row = blockIdx.x*4 + (threadIdx.x >> 6);
    int lane = threadIdx.x & 63;
    const float4* xr = (const float4*)(x + (size_t)row*D_);
    float4 v[4];
    float s = 0.f, q = 0.f;
#pragma unroll
    for (int i = 0; i < 4; ++i) {
        float4 a = xr[lane + i*64];
        if (NP == 4) {
#pragma unroll
            for (int z = 0; z < 4; ++z) {
                ushort4 p = ((const ushort4*)(parts + (size_t)z*pstride + (size_t)row*D_))[lane + i*64];
                a.x += b2f(p.x); a.y += b2f(p.y); a.z += b2f(p.z); a.w += b2f(p.w);
            }
        }
        v[i] = a;
        s += a.x+a.y+a.z+a.w;
        q += a.x*a.x+a.y*a.y+a.z*a.z+a.w*a.w;
    }
    if (NP == 4) {
#pragma unroll
        for (int i = 0; i < 4; ++i)
            ((float4*)(xout + (size_t)row*D_))[lane + i*64] = v[i];
    }
#pragma unroll
    for (int off = 1; off < 64; off <<= 1) {
        s += __shfl_xor(s, off, 64);
        q += __shfl_xor(q, off, 64);
    }
    float mean = s*(1.f/(float)D_);
    float var  = q*(1.f/(float)D_) - mean*mean;
    float rstd = rsqrtf(var + 1e-5f);
#pragma unroll
    for (int i = 0; i < 4; ++i) {
        int d0 = (lane + i*64)*4;
        ushort4 ov;
        ov.x = f2b((v[i].x-mean)*rstd*g[d0+0] + bb[d0+0]);
        ov.y = f2b((v[i].y-mean)*rstd*g[d0+1] + bb[d0+1]);
        ov.z = f2b((v[i].z-mean)*rstd*g[d0+2] + bb[d0+2]);
        ov.w = f2b((v[i].w-mean)*rstd*g[d0+3] + bb[d0+3]);
        ((ushort4*)(out + (size_t)row*D_))[lane + i*64] = ov;
    }
}

// ---------------------------------------------------------------------------
// MFMA bf16 GEMM: C(MxN) = act(A(MxK) @ Wt(NxK)^T + bias).
// 128x128 tile / 4 waves / BK=32 / 16x16x32 MFMA. 3-slab counted-vmcnt pipe.
// SPLITK>1: blockIdx.z owns K-chunk kc; ATOMIC ? f32 atomicAdd into outF
// : bf16 partial store to outB + z*partStride (reduced in fused LN/head).
// ---------------------------------------------------------------------------
template<int GELU_ACT, int SPLITK, int ATOMIC>
__global__ __launch_bounds__(256) void gemm_bt(const u16* __restrict__ A,
                                               const u16* __restrict__ Bt,
                                               const float* __restrict__ bias,
                                               float* __restrict__ outF,
                                               u16* __restrict__ outB,
                                               int M, int N, int K, int kc,
                                               size_t partStride)
{
    __shared__ __align__(16) u16 As[3*128*32];
    __shared__ __align__(16) u16 Bs[3*128*32];
    int tid = threadIdx.x;

    int gx = gridDim.x;
    int nwg = gx * gridDim.y;
    int id = blockIdx.y * gx + blockIdx.x;
    int q8 = nwg >> 3;                         // nwg % 8 == 0 for all launches
    int nid = (id & 7) * q8 + (id >> 3);       // contiguous tile range per XCD
    int n0 = (nid % gx) * 128;
    int m0 = (nid / gx) * 128;

    int wave = tid >> 6, lane = tid & 63;
    int wm = (wave >> 1) * 64, wn = (wave & 1) * 64;
    int lr = lane & 15, lq = lane >> 4;
    int slotRd = (lq ^ ((lr >> 1) & 3)) * 8;   // swizzled k-slot (u16 units)

    int srow = tid >> 2;                       // staging row 0..63 (+64)
    int sslot = (tid & 3) ^ ((srow >> 1) & 3); // swizzled source col-block

    int k0 = (SPLITK > 1) ? blockIdx.z * kc : 0;
    int nIt = ((SPLITK > 1) ? kc : K) >> 5;

    const u16* ap0 = A  + (size_t)(m0 + srow) * K + k0 + sslot * 8;
    const u16* ap1 = ap0 + (size_t)64 * K;
    const u16* bp0 = Bt + (size_t)(n0 + srow) * K + k0 + sslot * 8;
    const u16* bp1 = bp0 + (size_t)64 * K;

    // slab base pointers (rotate each iteration; reads from sA0, stage into sA2)
    u16 *sA0 = As, *sA1 = As + 4096, *sA2 = As + 8192;
    u16 *sB0 = Bs, *sB1 = Bs + 4096, *sB2 = Bs + 8192;
    int woff = wave * 512;

    f32x4 acc[4][4];
#pragma unroll
    for (int i = 0; i < 4; ++i)
#pragma unroll
        for (int j = 0; j < 4; ++j) acc[i][j] = (f32x4){0.f,0.f,0.f,0.f};

    // prologue: stage tiles 0 and 1 (order matters for vmcnt counting)
    gload16(ap0, sA0 + woff); gload16(ap1, sA0 + 2048 + woff);
    gload16(bp0, sB0 + woff); gload16(bp1, sB0 + 2048 + woff);
    ap0 += 32; ap1 += 32; bp0 += 32; bp1 += 32;
    gload16(ap0, sA1 + woff); gload16(ap1, sA1 + 2048 + woff);
    gload16(bp0, sB1 + woff); gload16(bp1, sB1 + 2048 + woff);
    ap0 += 32; ap1 += 32; bp0 += 32; bp1 += 32;

    for (int it = 0; it < nIt; ++it) {
        if (it + 1 < nIt) asm volatile("s_waitcnt vmcnt(4)" ::: "memory");
        else              asm volatile("s_waitcnt vmcnt(0)" ::: "memory");
        asm volatile("s_barrier" ::: "memory");
        if (it + 2 < nIt) {                    // stage tile t+2 into slab2
            gload16(ap0, sA2 + woff); gload16(ap1, sA2 + 2048 + woff);
            gload16(bp0, sB2 + woff); gload16(bp1, sB2 + 2048 + woff);
            ap0 += 32; ap1 += 32; bp0 += 32; bp1 += 32;
        }
        s16x8 af[4], bf[4];
#pragma unroll
        for (int i = 0; i < 4; ++i)
            af[i] = *(const s16x8*)(sA0 + (wm + i*16 + lr)*32 + slotRd);
#pragma unroll
        for (int j = 0; j < 4; ++j)
            bf[j] = *(const s16x8*)(sB0 + (wn + j*16 + lr)*32 + slotRd);
#pragma unroll
        for (int i = 0; i < 4; ++i)
#pragma unroll
            for (int j = 0; j < 4; ++j)
                acc[i][j] = __builtin_amdgcn_mfma_f32_16x16x32_bf16(af[i], bf[j], acc[i][j], 0, 0, 0);
        // rotate slabs: t+1 becomes current, freed slab becomes stage target
        u16* t0 = sA0; sA0 = sA1; sA1 = sA2; sA2 = t0;
        u16* t1 = sB0; sB0 = sB1; sB1 = sB2; sB2 = t1;
    }

    u16* outZ = (SPLITK > 1 && !ATOMIC) ? outB + (size_t)blockIdx.z * partStride : outB;
#pragma unroll
    for (int i = 0; i < 4; ++i) {
        int mbase = m0 + wm + i*16 + lq*4;
#pragma unroll
        for (int j = 0; j < 4; ++j) {
            int n = n0 + wn + j*16 + lr;
            float bvl = (SPLITK > 1) ? ((blockIdx.z == 0) ? bias[n] : 0.f) : bias[n];
#pragma unroll
            for (int r = 0; r < 4; ++r) {
                int m = mbase + r;
                float v = acc[i][j][r] + bvl;
                size_t off = (size_t)m*N + n;
                if (SPLITK > 1) {
                    if (ATOMIC) atomicAdd(outF + off, v);
                    else        outZ[off] = f2b(v);      // bf16 partial
                } else {
                    if (GELU_ACT) v = gelu_f(v);
                    if (outF) outF[off] = v;
                    if (outB) outB[off] = f2b(v);
                }
            }
        }
    }
}

// ---------------------------------------------------------------------------
// MFMA flash-style attention. Grid (B*H, 3): blockIdx.y = causal chunk c;
// block handles q-tiles c*4+w (one per wave) and stages only K/V rows
// < 64*(c+1). K staged row-major (coalesced), V transposed.
// Reads fused QKV buffer (row stride 3*D_: Q at +0, K at +D_, V at +2*D_).
// ---------------------------------------------------------------------------
__global__ __launch_bounds__(256) void attn_mfma_kernel(const u16* __restrict__ qkv,
                                                        u16* __restrict__ yb)
{
    __shared__ __align__(16) u16 Ks[192*72];
    __shared__ __align__(16) u16 Vt[64*200];
    __shared__ __align__(16) u16 Pch[4][16*40];

    int tid = threadIdx.x;
    int b = blockIdx.x >> 4, h = blockIdx.x & 15;
    int c = blockIdx.y;
    int nrows = (c + 1) * 64;
    int bT = b * T_;
    int colBase = h * 64;
    int w = tid >> 6, lane = tid & 63;
    int lr = lane & 15, lq = lane >> 4;
    const int S3 = 3 * D_;

    // stage K (row-major) and V (transposed), rows [0, nrows)
    for (int it = 0; it < (nrows >> 5); ++it) {
        int cc = it*256 + tid;
        int row = cc >> 3, ch = cc & 7;
        *(int4*)(Ks + row*72 + ch*8) =
            *(const int4*)(qkv + (size_t)(bT+row)*S3 + D_ + colBase + ch*8);
        union { int4 v; u16 s[8]; } rv;
        rv.v = *(const int4*)(qkv + (size_t)(bT+row)*S3 + 2*D_ + colBase + ch*8);
#pragma unroll
        for (int i2 = 0; i2 < 8; ++i2)
            Vt[(ch*8 + i2)*200 + row] = rv.s[i2];
    }
    __syncthreads();

    u16* Ch = Pch[w];
    int qt = c*4 + w;                 // this wave's q-tile (0..11)
    int tqb = qt * 16;

    // Q A-fragments (global, L2-hot)
    const u16* qrow = qkv + (size_t)(bT + tqb + lr)*S3 + colBase + lq*8;
    s16x8 af0 = *(const s16x8*)(qrow);
    s16x8 af1 = *(const s16x8*)(qrow + 32);

    // S = Q K^T  (C layout: row=lq*4+r, col=lr within j-tile)
    f32x4 sacc[12];
#pragma unroll
    for (int jt = 0; jt < 12; ++jt) {
        if (jt <= qt) {
            s16x8 bk0 = *(const s16x8*)(Ks + (jt*16 + lr)*72 + lq*8);
            s16x8 bk1 = *(const s16x8*)(Ks + (jt*16 + lr)*72 + 32 + lq*8);
            f32x4 a = (f32x4){0.f,0.f,0.f,0.f};
            a = __builtin_amdgcn_mfma_f32_16x16x32_bf16(af0, bk0, a, 0, 0, 0);
            a = __builtin_amdgcn_mfma_f32_16x16x32_bf16(af1, bk1, a, 0, 0, 0);
            sacc[jt] = a;
        }
    }

    // mask + row max
    float mrow[4] = {-1e30f,-1e30f,-1e30f,-1e30f};
#pragma unroll
    for (int jt = 0; jt < 12; ++jt) if (jt <= qt) {
#pragma unroll
        for (int r = 0; r < 4; ++r) {
            bool valid = (jt < qt) || (lr <= lq*4 + r);
            float s = valid ? sacc[jt][r]*0.125f : -1e30f;
            sacc[jt][r] = s;
            mrow[r] = fmaxf(mrow[r], s);
        }
    }
#pragma unroll
    for (int r = 0; r < 4; ++r) {
#pragma unroll
        for (int off = 1; off < 16; off <<= 1)
            mrow[r] = fmaxf(mrow[r], __shfl_xor(mrow[r], off, 64));
    }

    // exp + row sum (e kept in sacc registers)
    float lrow[4] = {0.f,0.f,0.f,0.f};
#pragma unroll
    for (int jt = 0; jt < 12; ++jt) if (jt <= qt) {
#pragma unroll
        for (int r = 0; r < 4; ++r) {
            float e = __expf(sacc[jt][r] - mrow[r]);
            sacc[jt][r] = e;
            lrow[r] += e;
        }
    }
#pragma unroll
    for (int r = 0; r < 4; ++r) {
#pragma unroll
        for (int off = 1; off < 16; off <<= 1)
            lrow[r] += __shfl_xor(lrow[r], off, 64);
        lrow[r] = 1.f / lrow[r];
    }

    // PV: per 32-key chunk, write P chunk (C->A layout via LDS), mfma
    int nkt = (qt + 2) >> 1;
    f32x4 oacc[4];
#pragma unroll
    for (int nt = 0; nt < 4; ++nt) oacc[nt] = (f32x4){0.f,0.f,0.f,0.f};

#pragma unroll
    for (int kt = 0; kt < 6; ++kt) if (kt < nkt) {
        int jt0 = 2*kt, jt1 = 2*kt + 1;
#pragma unroll
        for (int r = 0; r < 4; ++r) {
            u16 e0 = f2b(sacc[jt0][r]);
            u16 e1 = (jt1 <= qt) ? f2b(sacc[jt1][r]) : (u16)0;
            Ch[(lq*4 + r)*40 + lr]      = e0;
            Ch[(lq*4 + r)*40 + 16 + lr] = e1;
        }
        s16x8 ap = *(const s16x8*)(Ch + lr*40 + lq*8);
#pragma unroll
        for (int nt = 0; nt < 4; ++nt) {
            s16x8 bv = *(const s16x8*)(Vt + (nt*16 + lr)*200 + kt*32 + lq*8);
            oacc[nt] = __builtin_amdgcn_mfma_f32_16x16x32_bf16(ap, bv, oacc[nt], 0, 0, 0);
        }
    }

    // store O (C layout), normalized by 1/l
#pragma unroll
    for (int nt = 0; nt < 4; ++nt)
#pragma unroll
        for (int r = 0; r < 4; ++r)
            yb[(size_t)(bT + tqb + lq*4 + r)*D_ + colBase + nt*16 + lr] =
                f2b(oacc[nt][r] * lrow[r]);
}

// ---------------------------------------------------------------------------
// Final linear: out(BT x 27) = (xf [+4 bf16 partials]) @ lin_wT^T + lin_b.
// One wave per row; shuffle reduce per output column.
// ---------------------------------------------------------------------------
template<int NP>
__global__ __launch_bounds__(256) void final_kernel(const float* __restrict__ xf,
                                                    const u16* __restrict__ parts,
                                                    size_t pstride,
                                                    const float* __restrict__ lin_wT,
                                                    const float* __restrict__ lin_b,
                                                    float* __restrict__ out)
{
    int row = blockIdx.x*4 + (threadIdx.x >> 6);
    int lane = threadIdx.x & 63;
    const float4* xr = (const float4*)(xf + (size_t)row*D_);
    float4 x[4];
#pragma unroll
    for (int i = 0; i < 4; ++i) {
        float4 v = xr[lane + i*64];
        if (NP == 4) {
#pragma unroll
            for (int z = 0; z < 4; ++z) {
                ushort4 p = ((const ushort4*)(parts + (size_t)z*pstride + (size_t)row*D_))[lane + i*64];
                v.x += b2f(p.x); v.y += b2f(p.y); v.z += b2f(p.z); v.w += b2f(p.w);
            }
        }
        x[i] = v;
    }
#pragma unroll 1
    for (int c = 0; c < 27; ++c) {
        const float4* wr = (const float4*)(lin_wT + (size_t)c*D_);
        float a = 0.f;
#pragma unroll
        for (int i = 0; i < 4; ++i) {
            float4 wv = wr[lane + i*64];
            a += x[i].x*wv.x + x[i].y*wv.y + x[i].z*wv.z + x[i].w*wv.w;
        }
#pragma unroll
        for (int off = 1; off < 64; off <<= 1)
            a += __shfl_xor(a, off, 64);
        if (lane == 0) out[(size_t)row*27 + c] = a + lin_b[c];
    }
}

// ---------------------------------------------------------------------------
extern "C" void kernel_launch(void* const* d_in, const int* in_sizes, int n_in,
                              void* d_out, int out_size, void* d_ws, size_t ws_size,
                              hipStream_t stream)
{
    const float* states   = (const float*)d_in[0];
    const float* actions  = (const float*)d_in[1];
    const float* rtgs     = (const float*)d_in[2];
    const float* se_w1 = (const float*)d_in[5];
    const float* se_b1 = (const float*)d_in[6];
    const float* se_w2 = (const float*)d_in[7];
    const float* se_b2 = (const float*)d_in[8];
    const float* ae_w1 = (const float*)d_in[9];
    const float* ae_b1 = (const float*)d_in[10];
    const float* ae_w2 = (const float*)d_in[11];
    const float* ae_b2 = (const float*)d_in[12];
    const float* ad_bucket_w = (const float*)d_in[13];
    const float* ad_bucket_b = (const float*)d_in[14];
    const float* ad_ret_w = (const float*)d_in[15];
    const float* ad_res_w = (const float*)d_in[16];
    const float* pos_emb  = (const float*)d_in[17];
    const float* ln1_g = (const float*)d_in[18];
    const float* ln1_b = (const float*)d_in[19];
    const float* Wq = (const float*)d_in[20];
    const float* bq = (const float*)d_in[21];
    const float* Wk = (const float*)d_in[22];
    const float* bk = (const float*)d_in[23];
    const float* Wv = (const float*)d_in[24];
    const float* bv = (const float*)d_in[25];
    const float* Wp = (const float*)d_in[26];
    const float* bp = (const float*)d_in[27];
    const float* ln2_g = (const float*)d_in[28];
    const float* ln2_b = (const float*)d_in[29];
    const float* Wm1 = (const float*)d_in[30];
    const float* bm1 = (const float*)d_in[31];
    const float* Wm2 = (const float*)d_in[32];
    const float* bm2 = (const float*)d_in[33];
    const float* lin_w = (const float*)d_in[34];
    const float* lin_b = (const float*)d_in[35];

    char* w = (char*)d_ws;
    auto take = [&](size_t bytes) { char* p = w; w += (bytes + 255) & ~(size_t)255; return p; };

    float* xf   = (float*)take((size_t)BT_*D_*4);
    u16* hb     = (u16*)take((size_t)BT_*D_*2);        // ln out; also attn-y
    u16* qkvb   = (u16*)take((size_t)BT_*3*D_*2);      // fused QKV bf16
    char* scr   =        take((size_t)BT_*DF_*2);      // midb; embed scratch aliased
    u16*  midb  = (u16*)scr;
    u16*  tSb   = (u16*)scr;
    u16*  tAb   = (u16*)(scr + (size_t)BL_*D_*2);
    float* eS   = (float*)(scr + (size_t)2*BL_*D_*2);
    float* eA   = (float*)(scr + (size_t)2*BL_*D_*2 + (size_t)BL_*D_*4);
    float* eR   = (float*)(scr + (size_t)2*BL_*D_*2 + (size_t)2*BL_*D_*4);
    u16* pp     = (u16*)take((size_t)4*BT_*D_*2);      // P partials (4 bf16 slabs)
    u16* mq     = (u16*)take((size_t)4*BT_*D_*2);      // MLP2 partials (4 bf16 slabs)

    // pre-transposed bf16 weights (N x K)
    u16* Wqkvt = (u16*)take((size_t)NL_*3*D_*D_*2);
    u16* Wpt   = (u16*)take((size_t)NL_*D_*D_*2);
    u16* Wm1t  = (u16*)take((size_t)NL_*D_*DF_*2);
    u16* Wm2t  = (u16*)take((size_t)NL_*DF_*D_*2);
    u16* sw2t  = (u16*)take((size_t)D_*D_*2);
    u16* aw2t  = (u16*)take((size_t)D_*D_*2);
    float* bqkv= (float*)take((size_t)NL_*3*D_*4);
    float* lwT = (float*)take((size_t)27*D_*4);

    size_t ask = (size_t)(w - (char*)d_ws);
    bool bigWS = (ws_size >= ask);   // slabs available?
    // (if not, P/MLP2 fall back to atomic split-K into xf; LNs/final use NP=0)

    const size_t PSTRIDE = (size_t)BT_*D_;   // elements (u16)
    size_t DD = (size_t)D_*D_, DDF = (size_t)D_*DF_;

    // --- small prep + layer-0 weights (JIT: layer i+1 converted during layer i) ---
    pack_qkv_bias_kernel<<<72, 256, 0, stream>>>(bq, bk, bv, bqkv);
    tlin_kernel<<<4, 256, 0, stream>>>(lin_w, lwT);
    tconv_kernel<<<dim3(16,16), 256, 0, stream>>>(se_w2, sw2t, D_, D_);
    tconv_kernel<<<dim3(16,16), 256, 0, stream>>>(ae_w2, aw2t, D_, D_);
    tconvL_kernel<<<3072, 256, 0, stream>>>(Wq, Wk, Wv, Wp, Wm1, Wm2,
                                            Wqkvt, Wpt, Wm1t, Wm2t, 0);

    // --- embeddings ---
    embed1_kernel<<<4096, 256, 0, stream>>>(states,  se_w1, se_b1, tSb, 91);
    embed1_kernel<<<4096, 256, 0, stream>>>(actions, ae_w1, ae_b1, tAb, 27);
    gemm_bt<1,1,0><<<dim3(8,8), 256, 0, stream>>>(tSb, sw2t, se_b2, eS, nullptr, BL_, D_, D_, D_, 0);
    gemm_bt<0,1,0><<<dim3(8,8), 256, 0, stream>>>(tAb, aw2t, ae_b2, eA, nullptr, BL_, D_, D_, D_, 0);
    rtg_kernel<<<BL_, 128, 0, stream>>>(rtgs, ad_ret_w, ad_res_w, ad_bucket_w, ad_bucket_b, eR);
    assemble_kernel<<<(BT_*D_)/256, 256, 0, stream>>>(eR, eS, eA, pos_emb, xf);

    // --- transformer layers ---
    for (int i = 0; i < NL_; ++i) {
        // ln1: layers >0 also reduce the previous MLP2 partials into xf
        if (i > 0 && bigWS)
            ln_kernel<4><<<BT_/4, 256, 0, stream>>>(xf, mq, PSTRIDE, ln1_g + i*D_, ln1_b + i*D_, xf, hb);
        else
            ln_kernel<0><<<BT_/4, 256, 0, stream>>>(xf, nullptr, 0, ln1_g + i*D_, ln1_b + i*D_, nullptr, hb);
        // fused QKV
        gemm_bt<0,1,0><<<dim3(24,24), 256, 0, stream>>>(hb, Wqkvt + (size_t)i*3*DD, bqkv + i*3*D_,
                                                        nullptr, qkvb, BT_, 3*D_, D_, D_, 0);
        attn_mfma_kernel<<<dim3(B_*H_,3), 256, 0, stream>>>(qkvb, hb);   // y -> hb
        // JIT: convert next layer's weights now (L2/L3-hot when used)
        if (i + 1 < NL_)
            tconvL_kernel<<<3072, 256, 0, stream>>>(Wq, Wk, Wv, Wp, Wm1, Wm2,
                                                    Wqkvt, Wpt, Wm1t, Wm2t, i+1);
        // P projection: split-K x4, bf16 partial slabs (768 blocks = 3/CU)
        if (bigWS)
            gemm_bt<0,4,0><<<dim3(8,24,4), 256, 0, stream>>>(hb, Wpt + (size_t)i*DD, bp + i*D_,
                                                             nullptr, pp, BT_, D_, D_, 256, PSTRIDE);
        else
            gemm_bt<0,2,1><<<dim3(8,24,2), 256, 0, stream>>>(hb, Wpt + (size_t)i*DD, bp + i*D_,
                                                             xf, nullptr, BT_, D_, D_, 512, 0);
        // ln2 reduces P partials, updates xf, emits bf16 LN
        if (bigWS)
            ln_kernel<4><<<BT_/4, 256, 0, stream>>>(xf, pp, PSTRIDE, ln2_g + i*D_, ln2_b + i*D_, xf, hb);
        else
            ln_kernel<0><<<BT_/4, 256, 0, stream>>>(xf, nullptr, 0, ln2_g + i*D_, ln2_b + i*D_, nullptr, hb);
        // MLP
        gemm_bt<1,1,0><<<dim3(32,24), 256, 0, stream>>>(hb, Wm1t + (size_t)i*DDF, bm1 + i*DF_,
                                                        nullptr, midb, BT_, DF_, D_, D_, 0);
        if (bigWS)
            gemm_bt<0,4,0><<<dim3(8,24,4), 256, 0, stream>>>(midb, Wm2t + (size_t)i*DDF, bm2 + i*D_,
                                                             nullptr, mq, BT_, D_, DF_, 1024, PSTRIDE);
        else
            gemm_bt<0,2,1><<<dim3(8,24,2), 256, 0, stream>>>(midb, Wm2t + (size_t)i*DDF, bm2 + i*D_,
                                                             xf, nullptr, BT_, D_, DF_, 2048, 0);
    }

    // --- head (reduces last MLP2 partials on the fly) ---
    if (bigWS)
        final_kernel<4><<<BT_/4, 256, 0, stream>>>(xf, mq, PSTRIDE, lwT, lin_b, (float*)d_out);
    else
        final_kernel<0><<<BT_/4, 256, 0, stream>>>(xf, nullptr, 0, lwT, lin_b, (float*)d_out);
}